// Round 12
// baseline (627.612 us; speedup 1.0000x reference)
//
#include <hip/hip_runtime.h>
#include <cstddef>

#define B_   8
#define H_   80
#define W_   80
#define HW   6400
#define W2   82
#define HW2  6724   // 82*82 padded plane

typedef __attribute__((ext_vector_type(8)))  short short8;
typedef __attribute__((ext_vector_type(16))) float f32x16;

__device__ __forceinline__ float bf2f(ushort u) {
    return __uint_as_float(((unsigned)u) << 16);
}
__device__ __forceinline__ ushort f2bf(float f) {
    unsigned u = __float_as_uint(f);
    u += 0x7FFF + ((u >> 16) & 1);   // RNE
    return (ushort)(u >> 16);
}
__device__ __forceinline__ f32x16 mfma16(short8 a, short8 b, f32x16 c) {
    return __builtin_amdgcn_mfma_f32_32x32x16_bf16(a, b, c, 0, 0, 0);
}
// async global->LDS, 16B per lane (wave-uniform base + lane*16)
__device__ __forceinline__ void async16(const void* g, void* l) {
    __builtin_amdgcn_global_load_lds(
        (const __attribute__((address_space(1))) unsigned int*)g,
        (__attribute__((address_space(3))) unsigned int*)l, 16, 0, 0);
}
// swizzled fragment address in 64-ushort-stride LDS tile
__device__ __forceinline__ const ushort* frag_ptr(const ushort* sbuf, int row, int c8l) {
    return sbuf + row * 64 + ((c8l ^ (row & 7)) << 3);
}
// XCD-aware bijective blockIdx swizzle for 400-tile m-grids (400 % 8 == 0).
// Each XCD gets one contiguous 50-tile chunk (= one batch image; 3.44MB
// padded plane fits 4MB XCD L2).  [r9: FETCH 101.8->13.0 MB measured]
__device__ __forceinline__ int xcd_swz400(int bid) {
    return (bid & 7) * 50 + (bid >> 3);
}

// ---------------------------------------------------------------------------
// Zero the 1-px halos of BOTH padded NHWC buffers in one launch.
// ---------------------------------------------------------------------------
__global__ __launch_bounds__(256) void halo_zero2_kernel(
    ushort* __restrict__ xp1, ushort* __restrict__ xp2) {
    int idx = blockIdx.x * 256 + threadIdx.x;
    const int n1 = B_ * 324 * 32;   // C=256 -> 32 slots
    const int n2 = B_ * 324 * 16;   // C=128 -> 16 slots
    ushort* xp; int C, slots, i;
    if (idx < n1) { xp = xp1; C = 256; slots = 32; i = idx; }
    else if (idx < n1 + n2) { xp = xp2; C = 128; slots = 16; i = idx - n1; }
    else return;
    int sl = i % slots;
    int t = i / slots;
    int p = t % 324;
    int b = t / 324;
    int h, w;
    if (p < 164) { h = (p < 82) ? 0 : 81; w = p % 82; }
    else { int q = p - 164; w = (q < 80) ? 0 : 81; h = 1 + (q % 80); }
    *(uint4*)(xp + ((size_t)(b * HW2 + h * W2 + w)) * C + sl * 8) =
        make_uint4(0, 0, 0, 0);
}

// ---------------------------------------------------------------------------
// x fp32 NCHW -> xp bf16 padded NHWC [B][82][82][C].  grid (HW/64, C/64, B)
// ---------------------------------------------------------------------------
__global__ __launch_bounds__(256) void transpose_x_kernel(
    const float* __restrict__ x, ushort* __restrict__ xp, int C) {
    __shared__ float s[64][65];
    int hw0 = blockIdx.x * 64, c0 = blockIdx.y * 64, b = blockIdx.z;
    int t = threadIdx.x;
    int hl = t & 63, cq = t >> 6;
    #pragma unroll
    for (int i = 0; i < 16; i++) {
        int cl = cq * 16 + i;
        s[cl][hl] = x[((size_t)(b * C + c0 + cl)) * HW + hw0 + hl];
    }
    __syncthreads();
    int cl = t & 63, hq = t >> 6;
    #pragma unroll
    for (int i = 0; i < 16; i++) {
        int hl2 = hq * 16 + i;
        int hw = hw0 + hl2;
        int h = hw / W_, w = hw - h * W_;
        xp[((size_t)(b * HW2 + (h + 1) * W2 + w + 1)) * C + c0 + cl] = f2bf(s[cl][hl2]);
    }
}

// ---------------------------------------------------------------------------
// final: d_out[b][c][hw] = x[b][c][hw] + h2[b][hw][c]   (h2 dense NHWC)
// ---------------------------------------------------------------------------
__global__ __launch_bounds__(256) void final_add_kernel(
    const float* __restrict__ x, const ushort* __restrict__ h2,
    float* __restrict__ out, int C) {
    __shared__ float s[64][65];
    int hw0 = blockIdx.x * 64, c0 = blockIdx.y * 64, b = blockIdx.z;
    int t = threadIdx.x;
    int cl = t & 63, hq = t >> 6;
    #pragma unroll
    for (int i = 0; i < 16; i++) {
        int hl = hq * 16 + i;
        s[cl][hl] = bf2f(h2[((size_t)(b * HW + hw0 + hl)) * C + c0 + cl]);
    }
    __syncthreads();
    int hl = t & 63, cq = t >> 6;
    #pragma unroll
    for (int i = 0; i < 16; i++) {
        int cl2 = cq * 16 + i;
        size_t o = ((size_t)(b * C + c0 + cl2)) * HW + hw0 + hl;
        out[o] = x[o] + s[cl2][hl];
    }
}

// ---------------------------------------------------------------------------
// Combined weight prep: 8 jobs fp32 [OC][CIN][T] -> bf16 [OC][T][CIN]
// ---------------------------------------------------------------------------
struct WJobs {
    const float* src[8];
    ushort* dst[8];
    int cin[8], t[8];
    int start[9];
};

__global__ __launch_bounds__(256) void wprep_all_kernel(WJobs J) {
    int idx = blockIdx.x * 256 + threadIdx.x;
    if (idx >= J.start[8]) return;
    int j = 0;
    #pragma unroll
    for (int k = 1; k < 8; k++) if (idx >= J.start[k]) j = k;
    int i = idx - J.start[j];
    int CIN = J.cin[j], T = J.t[j];
    int oc = i / (CIN * T);
    int r = i - oc * CIN * T;
    int ci = r / T, t_ = r - ci * T;
    J.dst[j][((size_t)oc * T + t_) * CIN + ci] = f2bf(J.src[j][i]);
}

// ---------------------------------------------------------------------------
// Offset weight prep: pack 4 wanted channels (+28 zero pads) into [32][9][CIN]
// ---------------------------------------------------------------------------
__global__ void wprep_off_kernel(const float* __restrict__ wx_,
                                 const float* __restrict__ bx_,
                                 const float* __restrict__ wy_,
                                 const float* __restrict__ by_,
                                 ushort* __restrict__ dst,
                                 float* __restrict__ bdst, int CIN) {
    int idx = blockIdx.x * 256 + threadIdx.x;
    if (idx < 4) {
        const int chs[4] = {0, 2, 3, 5};
        bdst[idx] = (idx < 2) ? bx_[chs[idx]] : by_[chs[idx]];
    }
    if (idx >= 32 * 9 * CIN) return;
    int oc = idx / (9 * CIN);
    int r = idx - oc * 9 * CIN;
    int tap = r / CIN, ci = r - tap * CIN;
    float v = 0.f;
    if (oc < 4) {
        const int chs[4] = {0, 2, 3, 5};
        const float* src = (oc < 2) ? wx_ : wy_;
        v = src[((size_t)chs[oc] * CIN + ci) * 9 + tap];
    }
    dst[idx] = f2bf(v);
}

// ---------------------------------------------------------------------------
// Offset conv as shifted-row implicit GEMM, N=32 (4 real oc).  Epilogue
// computes tanh offset AND the packed bilinear lerp record for the (morph,
// outer-tap) pair this channel feeds: ltab[mp][b][hw] = {i0:u16,i1:u16, wl}.
// (mp = morph*2 + tap_half; channel mp <-> (morph=mp>>1, k3=(mp&1)*2)).
// grid (B*HW/128)
// ---------------------------------------------------------------------------
__global__ __launch_bounds__(256, 4) void off_gemm_kernel(
    const ushort* __restrict__ xp, const ushort* __restrict__ wB,
    const float* __restrict__ bias, uint2* __restrict__ ltab, int CIN) {
    __shared__ ushort s_a[128 * 64];
    __shared__ ushort s_bo[32 * 64];
    int tid = threadIdx.x;
    int m0 = xcd_swz400(blockIdx.x) * 128;
    int b = m0 / HW, hw0 = m0 - b * HW;
    int lane = tid & 63, wid = tid >> 6;
    int l31 = lane & 31, kg = lane >> 5;
    const ushort* xpb = xp + (size_t)b * HW2 * CIN;
    const ushort* asrc[4];
    #pragma unroll
    for (int j = 0; j < 4; j++) {
        int s = (wid * 4 + j) * 64 + lane;
        int r = s >> 3, c8p = s & 7;
        int c8l = c8p ^ (r & 7);
        int hw = hw0 + r;
        int h = hw / W_, w = hw - h * W_;
        asrc[j] = xpb + ((size_t)((h + 1) * W2 + (w + 1))) * CIN + c8l * 8;
    }
    int rB = tid >> 3;
    int cB = (tid & 7) ^ (rB & 7);
    f32x16 acc = {};
    int K = 9 * CIN, nk = K >> 6;
    int tap = 0, cioff = 0;
    for (int kc = 0; kc < nk; kc++) {
        int kg64 = kc << 6;
        int dy = tap / 3, dx = tap - dy * 3;
        int soff = ((dy - 1) * W2 + (dx - 1)) * CIN + cioff;   // wave-uniform
        __syncthreads();
        async16(wB + (size_t)rB * K + kg64 + cB * 8, s_bo + (size_t)tid * 8);
        #pragma unroll
        for (int j = 0; j < 4; j++) {
            int s = (wid * 4 + j) * 64 + lane;
            async16(asrc[j] + soff, s_a + s * 8);
        }
        __syncthreads();
        #pragma unroll
        for (int ks = 0; ks < 4; ks++) {
            int c8l = ks * 2 + kg;
            short8 af = *(const short8*)frag_ptr(s_a, wid * 32 + l31, c8l);
            short8 bf = *(const short8*)frag_ptr(s_bo, l31, c8l);
            acc = mfma16(af, bf, acc);
        }
        cioff += 64;
        if (cioff == CIN) { cioff = 0; tap++; }
    }
    int oc = l31;
    if (oc < 4) {
        float bb = bias[oc];
        int morph = oc >> 1;
        int k3 = (oc & 1) * 2;
        uint2* lt = ltab + ((size_t)oc * B_ + b) * HW;
        #pragma unroll
        for (int reg = 0; reg < 16; reg++) {
            int row = (reg & 3) + 8 * (reg >> 2) + 4 * kg;
            int m = m0 + wid * 32 + row;
            int hw = m - b * HW;
            int h = hw / W_, w = hw - h * W_;
            float bend = tanhf(acc[reg] + bb);
            int i0, i1; float wl;
            if (morph == 0) {
                float ys = fminf(fmaxf((float)h + bend, 0.f), 79.f);
                float y0f = floorf(ys); wl = ys - y0f;
                int y0 = (int)y0f, y1 = min(y0 + 1, 79);
                int xk = min(max(w + k3 - 1, 0), 79);
                i0 = (y0 + 1) * W2 + xk + 1; i1 = (y1 + 1) * W2 + xk + 1;
            } else {
                float xs = fminf(fmaxf((float)w + bend, 0.f), 79.f);
                float x0f = floorf(xs); wl = xs - x0f;
                int x0 = (int)x0f, x1 = min(x0 + 1, 79);
                int yk = min(max(h + k3 - 1, 0), 79);
                i0 = (yk + 1) * W2 + x0 + 1; i1 = (yk + 1) * W2 + x1 + 1;
            }
            lt[hw] = make_uint2((unsigned)i0 | ((unsigned)i1 << 16),
                                __float_as_uint(wl));
        }
    }
}

// ---------------------------------------------------------------------------
// FUSED conv3x3-GEMM + snake-conv-GEMM.  grid (400, OC/128, 3).
// z=0: conv3x3; z=1/2: dsc morph 0/1.  Lerp params from global ltab
// (precomputed in off_gemm) -> LDS exactly 32KB -> 5 blocks/CU.
// ---------------------------------------------------------------------------
__global__ __launch_bounds__(256, 5) void convdsc_kernel(
    const ushort* __restrict__ xp,
    const ushort* __restrict__ wC, const float* __restrict__ biasC,
    ushort* __restrict__ outC,
    const uint2* __restrict__ ltab,
    const ushort* __restrict__ Bwx, const float* __restrict__ biasx,
    ushort* __restrict__ outx,
    const ushort* __restrict__ Bwy, const float* __restrict__ biasy,
    ushort* __restrict__ outy, float* __restrict__ stat, int CIN, int OC) {
    __shared__ ushort s_a[128 * 64];
    __shared__ ushort s_b[128 * 64];
    int tid = threadIdx.x;
    int m0 = xcd_swz400(blockIdx.x) * 128, n0 = blockIdx.y * 128;
    int b = m0 / HW, hw0 = m0 - b * HW;     // 6400 % 128 == 0
    int lane = tid & 63, wid = tid >> 6;
    int l31 = lane & 31, kg = lane >> 5;
    int wm = wid >> 1, wn = wid & 1;

    if (blockIdx.z == 0) {
        // ---------------- conv3x3 path ----------------
        const ushort* xpb = xp + (size_t)b * HW2 * CIN;
        const ushort* asrc[4];
        #pragma unroll
        for (int j = 0; j < 4; j++) {
            int s = (wid * 4 + j) * 64 + lane;
            int r = s >> 3, c8p = s & 7;
            int c8l = c8p ^ (r & 7);
            int hw = hw0 + r;
            int h = hw / W_, w = hw - h * W_;
            asrc[j] = xpb + ((size_t)((h + 1) * W2 + (w + 1))) * CIN + c8l * 8;
        }
        f32x16 acc[2][2] = {};
        int K = 9 * CIN, nk = K >> 6;
        int tap = 0, cioff = 0;
        for (int kc = 0; kc < nk; kc++) {
            int kg64 = kc << 6;
            int dy = tap / 3, dx = tap - dy * 3;
            int soff = ((dy - 1) * W2 + (dx - 1)) * CIN + cioff;   // wave-uniform
            __syncthreads();
            #pragma unroll
            for (int j = 0; j < 4; j++) {
                int s = (wid * 4 + j) * 64 + lane;
                int r = s >> 3, c8p = s & 7;
                int c8l = c8p ^ (r & 7);
                async16(wC + (size_t)(n0 + r) * K + kg64 + c8l * 8, s_b + s * 8);
                async16(asrc[j] + soff, s_a + s * 8);
            }
            __syncthreads();
            #pragma unroll
            for (int ks = 0; ks < 4; ks++) {
                int c8l = ks * 2 + kg;
                short8 af0 = *(const short8*)frag_ptr(s_a, wm * 64 + l31, c8l);
                short8 af1 = *(const short8*)frag_ptr(s_a, wm * 64 + 32 + l31, c8l);
                short8 bf0 = *(const short8*)frag_ptr(s_b, wn * 64 + l31, c8l);
                short8 bf1 = *(const short8*)frag_ptr(s_b, wn * 64 + 32 + l31, c8l);
                acc[0][0] = mfma16(af0, bf0, acc[0][0]);
                acc[0][1] = mfma16(af0, bf1, acc[0][1]);
                acc[1][0] = mfma16(af1, bf0, acc[1][0]);
                acc[1][1] = mfma16(af1, bf1, acc[1][1]);
            }
            cioff += 64;
            if (cioff == CIN) { cioff = 0; tap++; }
        }
        int na = n0 + wn * 64 + l31, nb = na + 32;
        float ba = biasC[na], bb2 = biasC[nb];
        #pragma unroll
        for (int mf = 0; mf < 2; mf++) {
            #pragma unroll
            for (int reg = 0; reg < 16; reg++) {
                int row = (reg & 3) + 8 * (reg >> 2) + 4 * kg;
                int m = m0 + wm * 64 + mf * 32 + row;
                float v0 = acc[mf][0][reg] + ba;
                float v1 = acc[mf][1][reg] + bb2;
                v0 = v0 / (1.f + expf(-v0));
                v1 = v1 / (1.f + expf(-v1));
                outC[(size_t)m * OC + na] = f2bf(v0);
                outC[(size_t)m * OC + nb] = f2bf(v1);
            }
        }
        return;
    }

    // ---------------- dsc path ----------------
    int morph = blockIdx.z - 1;
    const ushort* Bw = morph ? Bwy : Bwx;
    const float* bias = morph ? biasy : biasx;
    ushort* out = morph ? outy : outx;
    float* statm = stat + (size_t)morph * B_ * 256 * 2;
    const ushort* xb = xp + (size_t)b * HW2 * CIN;
    const ushort* asrcC[4];
    #pragma unroll
    for (int j = 0; j < 4; j++) {
        int s = (wid * 4 + j) * 64 + lane;
        int r = s >> 3, c8p = s & 7;
        int c8l = c8p ^ (r & 7);
        int hw = hw0 + r;
        int h = hw / W_, w = hw - h * W_;
        asrcC[j] = xb + ((size_t)((h + 1) * W2 + (w + 1))) * CIN + c8l * 8;
    }
    f32x16 acc[2][2] = {};
    int K = 3 * CIN, nk = K >> 6;
    for (int kc = 0; kc < nk; kc++) {
        int kg64 = kc << 6;
        int k3 = kg64 / CIN;              // uniform per kc (64 | CIN)
        int cioff = kg64 - k3 * CIN;
        __syncthreads();
        #pragma unroll
        for (int j = 0; j < 4; j++) {
            int s = (wid * 4 + j) * 64 + lane;
            int r = s >> 3, c8p = s & 7;
            int c8l = c8p ^ (r & 7);
            async16(Bw + (size_t)(n0 + r) * K + kg64 + c8l * 8, s_b + s * 8);
        }
        if (k3 == 1) {
            // center tap: wl==0, sampled == x[center] -> pure DMA
            #pragma unroll
            for (int j = 0; j < 4; j++) {
                int s = (wid * 4 + j) * 64 + lane;
                async16(asrcC[j] + cioff, s_a + s * 8);
            }
        } else {
            const uint2* ltk = ltab
                + ((size_t)(morph * 2 + (k3 >> 1)) * B_ + b) * HW + hw0;
            #pragma unroll
            for (int i = 0; i < 4; i++) {
                int s = i * 256 + tid;
                int r = s >> 3, c8p = s & 7;
                int c8l = c8p ^ (r & 7);
                int ci = cioff + c8l * 8;
                uint2 rec = ltk[r];
                int i0 = rec.x & 0xFFFF;
                int i1 = rec.x >> 16;
                float wl = __uint_as_float(rec.y);
                uint4 u0 = *(const uint4*)(xb + (size_t)i0 * CIN + ci);
                uint4 u1 = *(const uint4*)(xb + (size_t)i1 * CIN + ci);
                const ushort* p0 = (const ushort*)&u0;
                const ushort* p1 = (const ushort*)&u1;
                uint ov[4];
                #pragma unroll
                for (int j = 0; j < 4; j++) {
                    float a0 = bf2f(p0[2 * j]),     b0 = bf2f(p1[2 * j]);
                    float a1 = bf2f(p0[2 * j + 1]), b1 = bf2f(p1[2 * j + 1]);
                    float r0 = a0 + (b0 - a0) * wl;
                    float r1 = a1 + (b1 - a1) * wl;
                    asm("v_cvt_pk_bf16_f32 %0, %1, %2"
                        : "=v"(ov[j]) : "v"(r0), "v"(r1));
                }
                *(uint4*)(s_a + s * 8) = *(uint4*)ov;
            }
        }
        __syncthreads();
        #pragma unroll
        for (int ks = 0; ks < 4; ks++) {
            int c8l = ks * 2 + kg;
            short8 af0 = *(const short8*)frag_ptr(s_a, wm * 64 + l31, c8l);
            short8 af1 = *(const short8*)frag_ptr(s_a, wm * 64 + 32 + l31, c8l);
            short8 bf0 = *(const short8*)frag_ptr(s_b, wn * 64 + l31, c8l);
            short8 bf1 = *(const short8*)frag_ptr(s_b, wn * 64 + 32 + l31, c8l);
            acc[0][0] = mfma16(af0, bf0, acc[0][0]);
            acc[0][1] = mfma16(af0, bf1, acc[0][1]);
            acc[1][0] = mfma16(af1, bf0, acc[1][0]);
            acc[1][1] = mfma16(af1, bf1, acc[1][1]);
        }
    }
    int na = n0 + wn * 64 + l31, nb = na + 32;
    float ba = bias[na], bb2 = bias[nb];
    float ssum0 = 0.f, ssq0 = 0.f, ssum1 = 0.f, ssq1 = 0.f;
    #pragma unroll
    for (int mf = 0; mf < 2; mf++) {
        #pragma unroll
        for (int reg = 0; reg < 16; reg++) {
            int row = (reg & 3) + 8 * (reg >> 2) + 4 * kg;
            int m = m0 + wm * 64 + mf * 32 + row;
            float v0 = acc[mf][0][reg] + ba;
            float v1 = acc[mf][1][reg] + bb2;
            ssum0 += v0; ssq0 += v0 * v0;
            ssum1 += v1; ssq1 += v1 * v1;
            out[(size_t)m * OC + na] = f2bf(v0);
            out[(size_t)m * OC + nb] = f2bf(v1);
        }
    }
    ssum0 += __shfl_xor(ssum0, 32);
    ssq0  += __shfl_xor(ssq0, 32);
    ssum1 += __shfl_xor(ssum1, 32);
    ssq1  += __shfl_xor(ssq1, 32);
    if (kg == 0) {
        float* st0 = statm + ((size_t)b * OC + na) * 2;
        atomicAdd(st0, ssum0);
        atomicAdd(st0 + 1, ssq0);
        float* st1 = statm + ((size_t)b * OC + nb) * 2;
        atomicAdd(st1, ssum1);
        atomicAdd(st1 + 1, ssq1);
    }
}

// ---------------------------------------------------------------------------
// 128x128 MFMA GEMM over concat-A (3 parts).  Part 0 staged via DMA;
// parts 1/2 staged via VGPR with FUSED GroupNorm scale/shift + ReLU.
// SiLU epilogue (line-complete stores); optional padded output.
// XCD-swizzled m-tiles, 32KB LDS -> 5 blocks/CU.  grid (400, N/128)
// ---------------------------------------------------------------------------
__global__ __launch_bounds__(256, 5) void gemm128_kernel(
    const ushort* __restrict__ a0, const ushort* __restrict__ a1,
    const ushort* __restrict__ a2, int part_k,
    const ushort* __restrict__ Bw, int K, int N,
    const float* __restrict__ bias,
    const float* __restrict__ scx, const float* __restrict__ shx,
    const float* __restrict__ scy, const float* __restrict__ shy,
    ushort* __restrict__ out, int epi_silu, int out_pad) {
    __shared__ ushort s_a[128 * 64];
    __shared__ ushort s_b[128 * 64];
    int tid = threadIdx.x;
    int m0 = xcd_swz400(blockIdx.x) * 128, n0 = blockIdx.y * 128;
    int b = m0 / HW;                        // uniform (6400 % 128 == 0)
    int lane = tid & 63, wid = tid >> 6;
    int l31 = lane & 31, kg = lane >> 5;
    int wm = wid >> 1, wn = wid & 1;
    f32x16 acc[2][2] = {};
    int nk = K >> 6;
    for (int kc = 0; kc < nk; kc++) {
        int kg64 = kc << 6;
        int part = kg64 / part_k;
        int koff = kg64 - part * part_k;
        __syncthreads();
        #pragma unroll
        for (int j = 0; j < 4; j++) {
            int s = (wid * 4 + j) * 64 + lane;
            int r = s >> 3, c8p = s & 7;
            int c8l = c8p ^ (r & 7);
            async16(Bw + (size_t)(n0 + r) * K + kg64 + c8l * 8, s_b + s * 8);
        }
        if (part == 0) {
            #pragma unroll
            for (int j = 0; j < 4; j++) {
                int s = (wid * 4 + j) * 64 + lane;
                int r = s >> 3, c8p = s & 7;
                int c8l = c8p ^ (r & 7);
                async16(a0 + (size_t)(m0 + r) * part_k + koff + c8l * 8,
                        s_a + s * 8);
            }
        } else {
            const ushort* ap = (part == 1) ? a1 : a2;
            const float* scp = ((part == 1) ? scx : scy) + (size_t)b * part_k;
            const float* shp = ((part == 1) ? shx : shy) + (size_t)b * part_k;
            #pragma unroll
            for (int i = 0; i < 4; i++) {
                int s = i * 256 + tid;
                int r = s >> 3, c8p = s & 7;
                int c8l = c8p ^ (r & 7);
                int ch = koff + c8l * 8;
                uint4 u = *(const uint4*)(ap + (size_t)(m0 + r) * part_k + ch);
                float4 c0 = *(const float4*)(scp + ch);
                float4 c1 = *(const float4*)(scp + ch + 4);
                float4 h0 = *(const float4*)(shp + ch);
                float4 h1 = *(const float4*)(shp + ch + 4);
                const ushort* pv = (const ushort*)&u;
                uint ov[4];
                float r0, r1;
                r0 = fmaxf(bf2f(pv[0]) * c0.x + h0.x, 0.f);
                r1 = fmaxf(bf2f(pv[1]) * c0.y + h0.y, 0.f);
                asm("v_cvt_pk_bf16_f32 %0, %1, %2" : "=v"(ov[0]) : "v"(r0), "v"(r1));
                r0 = fmaxf(bf2f(pv[2]) * c0.z + h0.z, 0.f);
                r1 = fmaxf(bf2f(pv[3]) * c0.w + h0.w, 0.f);
                asm("v_cvt_pk_bf16_f32 %0, %1, %2" : "=v"(ov[1]) : "v"(r0), "v"(r1));
                r0 = fmaxf(bf2f(pv[4]) * c1.x + h1.x, 0.f);
                r1 = fmaxf(bf2f(pv[5]) * c1.y + h1.y, 0.f);
                asm("v_cvt_pk_bf16_f32 %0, %1, %2" : "=v"(ov[2]) : "v"(r0), "v"(r1));
                r0 = fmaxf(bf2f(pv[6]) * c1.z + h1.z, 0.f);
                r1 = fmaxf(bf2f(pv[7]) * c1.w + h1.w, 0.f);
                asm("v_cvt_pk_bf16_f32 %0, %1, %2" : "=v"(ov[3]) : "v"(r0), "v"(r1));
                *(uint4*)(s_a + s * 8) = *(uint4*)ov;
            }
        }
        __syncthreads();
        #pragma unroll
        for (int ks = 0; ks < 4; ks++) {
            int c8l = ks * 2 + kg;
            short8 af0 = *(const short8*)frag_ptr(s_a, wm * 64 + l31, c8l);
            short8 af1 = *(const short8*)frag_ptr(s_a, wm * 64 + 32 + l31, c8l);
            short8 bf0 = *(const short8*)frag_ptr(s_b, wn * 64 + l31, c8l);
            short8 bf1 = *(const short8*)frag_ptr(s_b, wn * 64 + 32 + l31, c8l);
            acc[0][0] = mfma16(af0, bf0, acc[0][0]);
            acc[0][1] = mfma16(af0, bf1, acc[0][1]);
            acc[1][0] = mfma16(af1, bf0, acc[1][0]);
            acc[1][1] = mfma16(af1, bf1, acc[1][1]);
        }
    }
    int na = n0 + wn * 64 + l31, nb = na + 32;
    float ba = bias[na], bb2 = bias[nb];
    #pragma unroll
    for (int mf = 0; mf < 2; mf++) {
        #pragma unroll
        for (int reg = 0; reg < 16; reg++) {
            int row = (reg & 3) + 8 * (reg >> 2) + 4 * kg;
            int m = m0 + wm * 64 + mf * 32 + row;
            float v0 = acc[mf][0][reg] + ba;
            float v1 = acc[mf][1][reg] + bb2;
            if (epi_silu) {
                v0 = v0 / (1.f + expf(-v0));
                v1 = v1 / (1.f + expf(-v1));
            }
            size_t mm = (size_t)m;
            if (out_pad) {
                int bb_ = m / HW, hw = m - bb_ * HW;
                int h = hw / W_, w = hw - h * W_;
                mm = (size_t)bb_ * HW2 + (h + 1) * W2 + w + 1;
            }
            out[mm * N + na] = f2bf(v0);
            out[mm * N + nb] = f2bf(v1);
        }
    }
}

// ---------------------------------------------------------------------------
// GN finalize from fused per-channel sums: grid (ceil(B*C/256), 2)
// ---------------------------------------------------------------------------
__global__ void gn_finalize_kernel(const float* __restrict__ stat,
                                   const float* __restrict__ gx,
                                   const float* __restrict__ bx,
                                   const float* __restrict__ gy,
                                   const float* __restrict__ by,
                                   float* __restrict__ scx, float* __restrict__ shx,
                                   float* __restrict__ scy, float* __restrict__ shy,
                                   int C) {
    int idx = blockIdx.x * 256 + threadIdx.x;
    if (idx >= B_ * C) return;
    int which = blockIdx.y;
    const float* gamma = which ? gy : gx;
    const float* beta  = which ? by : bx;
    float* sc = which ? scy : scx;
    float* sh = which ? shy : shx;
    int b = idx / C, c = idx - b * C;
    const float* st = stat + (size_t)which * B_ * 256 * 2
                    + ((size_t)b * C + (c & ~3)) * 2;
    float s  = st[0] + st[2] + st[4] + st[6];
    float sq = st[1] + st[3] + st[5] + st[7];
    float mean = s / (4.f * HW);
    float var = sq / (4.f * HW) - mean * mean;
    float rs = rsqrtf(var + 1e-5f);
    float scale = rs * gamma[c];
    sc[idx] = scale;
    sh[idx] = beta[c] - mean * scale;
}

// ---------------------------------------------------------------------------
// Host orchestration
// ---------------------------------------------------------------------------
struct BlkBuf {
    ushort *xp, *abuf, *bqx, *bqy, *hout;
    uint2 *ltab;
    float *stat, *scx, *shx, *scy, *shy, *boff;
    ushort *wc, *wdx, *wdy, *wf, *woff;
};

static void run_block(const BlkBuf& B, int CIN, int OC,
                      const float* const* P, int out_pad, hipStream_t stream) {
    dim3 blk(256);
    off_gemm_kernel<<<dim3(B_ * HW / 128), blk, 0, stream>>>(
        B.xp, B.woff, B.boff, B.ltab, CIN);
    convdsc_kernel<<<dim3(400, OC / 128, 3), blk, 0, stream>>>(
        B.xp, B.wc, P[1], B.abuf,
        B.ltab, B.wdx, P[5], B.bqx, B.wdy, P[11], B.bqy, B.stat, CIN, OC);
    int fgrid = (B_ * OC + 255) / 256;
    gn_finalize_kernel<<<dim3(fgrid, 2), blk, 0, stream>>>(
        B.stat, P[6], P[7], P[12], P[13], B.scx, B.shx, B.scy, B.shy, OC);
    gemm128_kernel<<<dim3(400, OC / 128), blk, 0, stream>>>(
        B.abuf, B.bqx, B.bqy, OC, B.wf, 3 * OC, OC, P[15],
        B.scx, B.shx, B.scy, B.shy, B.hout, 1, out_pad);
}

extern "C" void kernel_launch(void* const* d_in, const int* in_sizes, int n_in,
                              void* d_out, int out_size, void* d_ws, size_t ws_size,
                              hipStream_t stream) {
    const float* x = (const float*)d_in[0];
    const float* P1[16];
    const float* P2[16];
    for (int i = 0; i < 16; i++) {
        P1[i] = (const float*)d_in[1 + i];
        P2[i] = (const float*)d_in[17 + i];
    }
    char* base = (char*)d_ws;
    size_t off = 0;
    auto alloc = [&](size_t bytes) -> char* {
        off = (off + 255) & ~(size_t)255;
        char* p = base + off;
        off += bytes;
        return p;
    };
    ushort* xp1  = (ushort*)alloc((size_t)B_ * HW2 * 256 * 2);  // padded block1 input
    ushort* xp2  = (ushort*)alloc((size_t)B_ * HW2 * 128 * 2);  // padded block2 input
    ushort* abuf = (ushort*)alloc((size_t)B_ * HW * 256 * 2);
    ushort* bqx  = (ushort*)alloc((size_t)B_ * HW * 256 * 2);
    ushort* bqy  = (ushort*)alloc((size_t)B_ * HW * 256 * 2);
    uint2*  ltab = (uint2*)alloc((size_t)4 * B_ * HW * 8);   // lerp records
    float*  stat1 = (float*)alloc((size_t)2 * B_ * 256 * 2 * 4);
    float*  stat2 = (float*)alloc((size_t)2 * B_ * 256 * 2 * 4);
    float*  scx  = (float*)alloc(B_ * 256 * 4);
    float*  shx  = (float*)alloc(B_ * 256 * 4);
    float*  scy  = (float*)alloc(B_ * 256 * 4);
    float*  shy  = (float*)alloc(B_ * 256 * 4);
    ushort* wc1  = (ushort*)alloc((size_t)128 * 9 * 256 * 2);
    ushort* wc2  = (ushort*)alloc((size_t)256 * 9 * 128 * 2);
    ushort* wdx1 = (ushort*)alloc((size_t)128 * 3 * 256 * 2);
    ushort* wdy1 = (ushort*)alloc((size_t)128 * 3 * 256 * 2);
    ushort* wdx2 = (ushort*)alloc((size_t)256 * 3 * 128 * 2);
    ushort* wdy2 = (ushort*)alloc((size_t)256 * 3 * 128 * 2);
    ushort* wf1  = (ushort*)alloc((size_t)128 * 384 * 2);
    ushort* wf2  = (ushort*)alloc((size_t)256 * 768 * 2);
    ushort* wo1  = (ushort*)alloc((size_t)32 * 9 * 256 * 2);
    ushort* wo2  = (ushort*)alloc((size_t)32 * 9 * 128 * 2);
    float*  bo1  = (float*)alloc(32 * 4);
    float*  bo2  = (float*)alloc(32 * 4);
    // h2 (block2 dense output, [B][HW][256]) aliases xp1 (dead after block1)
    ushort* h2 = xp1;

    dim3 blk(256);
    // both stat buffers zeroed up-front (no mid-pipeline memset dispatches)
    hipMemsetAsync(stat1, 0, (size_t)2 * B_ * 256 * 2 * 4, stream);
    hipMemsetAsync(stat2, 0, (size_t)2 * B_ * 256 * 2 * 4, stream);
    // zero halos of both padded buffers in one launch
    {
        int total = B_ * 324 * 32 + B_ * 324 * 16;
        halo_zero2_kernel<<<(total + 255) / 256, blk, 0, stream>>>(xp1, xp2);
    }

    // combined weight prep (8 jobs, 1 launch)
    {
        WJobs J;
        const float* srcs[8] = {P1[0], P1[4], P1[10], P1[14],
                                P2[0], P2[4], P2[10], P2[14]};
        ushort* dsts[8] = {wc1, wdx1, wdy1, wf1, wc2, wdx2, wdy2, wf2};
        int cins[8] = {256, 256, 256, 384, 128, 128, 128, 768};
        int ts[8]   = {9, 3, 3, 1, 9, 3, 3, 1};
        int ocs[8]  = {128, 128, 128, 128, 256, 256, 256, 256};
        int acc = 0;
        for (int j = 0; j < 8; j++) {
            J.src[j] = srcs[j]; J.dst[j] = dsts[j];
            J.cin[j] = cins[j]; J.t[j] = ts[j];
            J.start[j] = acc;
            acc += ocs[j] * cins[j] * ts[j];
        }
        J.start[8] = acc;
        wprep_all_kernel<<<(acc + 255) / 256, blk, 0, stream>>>(J);
    }
    wprep_off_kernel<<<(32 * 9 * 256 + 255) / 256, blk, 0, stream>>>(
        P1[2], P1[3], P1[8], P1[9], wo1, bo1, 256);
    wprep_off_kernel<<<(32 * 9 * 128 + 255) / 256, blk, 0, stream>>>(
        P2[2], P2[3], P2[8], P2[9], wo2, bo2, 128);

    transpose_x_kernel<<<dim3(100, 4, B_), blk, 0, stream>>>(x, xp1, 256);

    BlkBuf B1 = {xp1, abuf, bqx, bqy, xp2, ltab, stat1, scx, shx, scy, shy,
                 bo1, wc1, wdx1, wdy1, wf1, wo1};
    run_block(B1, 256, 128, P1, /*out_pad=*/1, stream);

    BlkBuf B2 = {xp2, abuf, bqx, bqy, h2, ltab, stat2, scx, shx, scy, shy,
                 bo2, wc2, wdx2, wdy2, wf2, wo2};
    run_block(B2, 128, 256, P2, /*out_pad=*/0, stream);

    final_add_kernel<<<dim3(100, 4, B_), blk, 0, stream>>>(x, h2, (float*)d_out, 256);
}

// Round 13
// 502.883 us; speedup vs baseline: 1.2480x; 1.2480x over previous
//
#include <hip/hip_runtime.h>
#include <cstddef>

#define B_   8
#define H_   80
#define W_   80
#define HW   6400
#define W2   82
#define HW2  6724   // 82*82 padded plane

typedef __attribute__((ext_vector_type(8)))  short short8;
typedef __attribute__((ext_vector_type(16))) float f32x16;

__device__ __forceinline__ float bf2f(ushort u) {
    return __uint_as_float(((unsigned)u) << 16);
}
__device__ __forceinline__ ushort f2bf(float f) {
    unsigned u = __float_as_uint(f);
    u += 0x7FFF + ((u >> 16) & 1);   // RNE
    return (ushort)(u >> 16);
}
__device__ __forceinline__ f32x16 mfma16(short8 a, short8 b, f32x16 c) {
    return __builtin_amdgcn_mfma_f32_32x32x16_bf16(a, b, c, 0, 0, 0);
}
// async global->LDS, 16B per lane (wave-uniform base + lane*16)
__device__ __forceinline__ void async16(const void* g, void* l) {
    __builtin_amdgcn_global_load_lds(
        (const __attribute__((address_space(1))) unsigned int*)g,
        (__attribute__((address_space(3))) unsigned int*)l, 16, 0, 0);
}
// swizzled fragment address in 64-ushort-stride LDS tile
__device__ __forceinline__ const ushort* frag_ptr(const ushort* sbuf, int row, int c8l) {
    return sbuf + row * 64 + ((c8l ^ (row & 7)) << 3);
}
// XCD-aware bijective blockIdx swizzle for 400-tile m-grids (400 % 8 == 0).
// Each XCD gets one contiguous 50-tile chunk (= one batch image; 3.44MB
// padded plane fits 4MB XCD L2).  [r9: FETCH 101.8->13.0 MB measured]
__device__ __forceinline__ int xcd_swz400(int bid) {
    return (bid & 7) * 50 + (bid >> 3);
}

// ---------------------------------------------------------------------------
// Zero the 1-px halos of BOTH padded NHWC buffers in one launch.
// ---------------------------------------------------------------------------
__global__ __launch_bounds__(256) void halo_zero2_kernel(
    ushort* __restrict__ xp1, ushort* __restrict__ xp2) {
    int idx = blockIdx.x * 256 + threadIdx.x;
    const int n1 = B_ * 324 * 32;   // C=256 -> 32 slots
    const int n2 = B_ * 324 * 16;   // C=128 -> 16 slots
    ushort* xp; int C, slots, i;
    if (idx < n1) { xp = xp1; C = 256; slots = 32; i = idx; }
    else if (idx < n1 + n2) { xp = xp2; C = 128; slots = 16; i = idx - n1; }
    else return;
    int sl = i % slots;
    int t = i / slots;
    int p = t % 324;
    int b = t / 324;
    int h, w;
    if (p < 164) { h = (p < 82) ? 0 : 81; w = p % 82; }
    else { int q = p - 164; w = (q < 80) ? 0 : 81; h = 1 + (q % 80); }
    *(uint4*)(xp + ((size_t)(b * HW2 + h * W2 + w)) * C + sl * 8) =
        make_uint4(0, 0, 0, 0);
}

// ---------------------------------------------------------------------------
// x fp32 NCHW -> xp bf16 padded NHWC [B][82][82][C].  grid (HW/64, C/64, B)
// ---------------------------------------------------------------------------
__global__ __launch_bounds__(256) void transpose_x_kernel(
    const float* __restrict__ x, ushort* __restrict__ xp, int C) {
    __shared__ float s[64][65];
    int hw0 = blockIdx.x * 64, c0 = blockIdx.y * 64, b = blockIdx.z;
    int t = threadIdx.x;
    int hl = t & 63, cq = t >> 6;
    #pragma unroll
    for (int i = 0; i < 16; i++) {
        int cl = cq * 16 + i;
        s[cl][hl] = x[((size_t)(b * C + c0 + cl)) * HW + hw0 + hl];
    }
    __syncthreads();
    int cl = t & 63, hq = t >> 6;
    #pragma unroll
    for (int i = 0; i < 16; i++) {
        int hl2 = hq * 16 + i;
        int hw = hw0 + hl2;
        int h = hw / W_, w = hw - h * W_;
        xp[((size_t)(b * HW2 + (h + 1) * W2 + w + 1)) * C + c0 + cl] = f2bf(s[cl][hl2]);
    }
}

// ---------------------------------------------------------------------------
// final: d_out[b][c][hw] = x[b][c][hw] + h2[b][hw][c]   (h2 dense NHWC)
// ---------------------------------------------------------------------------
__global__ __launch_bounds__(256) void final_add_kernel(
    const float* __restrict__ x, const ushort* __restrict__ h2,
    float* __restrict__ out, int C) {
    __shared__ float s[64][65];
    int hw0 = blockIdx.x * 64, c0 = blockIdx.y * 64, b = blockIdx.z;
    int t = threadIdx.x;
    int cl = t & 63, hq = t >> 6;
    #pragma unroll
    for (int i = 0; i < 16; i++) {
        int hl = hq * 16 + i;
        s[cl][hl] = bf2f(h2[((size_t)(b * HW + hw0 + hl)) * C + c0 + cl]);
    }
    __syncthreads();
    int hl = t & 63, cq = t >> 6;
    #pragma unroll
    for (int i = 0; i < 16; i++) {
        int cl2 = cq * 16 + i;
        size_t o = ((size_t)(b * C + c0 + cl2)) * HW + hw0 + hl;
        out[o] = x[o] + s[cl2][hl];
    }
}

// ---------------------------------------------------------------------------
// Combined weight prep: 8 jobs fp32 [OC][CIN][T] -> bf16 [OC][T][CIN]
// ---------------------------------------------------------------------------
struct WJobs {
    const float* src[8];
    ushort* dst[8];
    int cin[8], t[8];
    int start[9];
};

__global__ __launch_bounds__(256) void wprep_all_kernel(WJobs J) {
    int idx = blockIdx.x * 256 + threadIdx.x;
    if (idx >= J.start[8]) return;
    int j = 0;
    #pragma unroll
    for (int k = 1; k < 8; k++) if (idx >= J.start[k]) j = k;
    int i = idx - J.start[j];
    int CIN = J.cin[j], T = J.t[j];
    int oc = i / (CIN * T);
    int r = i - oc * CIN * T;
    int ci = r / T, t_ = r - ci * T;
    J.dst[j][((size_t)oc * T + t_) * CIN + ci] = f2bf(J.src[j][i]);
}

// ---------------------------------------------------------------------------
// Offset weight prep: pack 4 wanted channels (+28 zero pads) into [32][9][CIN]
// ---------------------------------------------------------------------------
__global__ void wprep_off_kernel(const float* __restrict__ wx_,
                                 const float* __restrict__ bx_,
                                 const float* __restrict__ wy_,
                                 const float* __restrict__ by_,
                                 ushort* __restrict__ dst,
                                 float* __restrict__ bdst, int CIN) {
    int idx = blockIdx.x * 256 + threadIdx.x;
    if (idx < 4) {
        const int chs[4] = {0, 2, 3, 5};
        bdst[idx] = (idx < 2) ? bx_[chs[idx]] : by_[chs[idx]];
    }
    if (idx >= 32 * 9 * CIN) return;
    int oc = idx / (9 * CIN);
    int r = idx - oc * 9 * CIN;
    int tap = r / CIN, ci = r - tap * CIN;
    float v = 0.f;
    if (oc < 4) {
        const int chs[4] = {0, 2, 3, 5};
        const float* src = (oc < 2) ? wx_ : wy_;
        v = src[((size_t)chs[oc] * CIN + ci) * 9 + tap];
    }
    dst[idx] = f2bf(v);
}

// ---------------------------------------------------------------------------
// Offset conv as shifted-row implicit GEMM, N=32 (4 real oc).  Epilogue
// computes tanh offset AND the packed bilinear lerp record for the (morph,
// outer-tap) pair this channel feeds: ltab[mp][b][hw] = {i0:u16,i1:u16, wl}.
// grid (B*HW/128)
// ---------------------------------------------------------------------------
__global__ __launch_bounds__(256, 4) void off_gemm_kernel(
    const ushort* __restrict__ xp, const ushort* __restrict__ wB,
    const float* __restrict__ bias, uint2* __restrict__ ltab, int CIN) {
    __shared__ ushort s_a[128 * 64];
    __shared__ ushort s_bo[32 * 64];
    int tid = threadIdx.x;
    int m0 = xcd_swz400(blockIdx.x) * 128;
    int b = m0 / HW, hw0 = m0 - b * HW;
    int lane = tid & 63, wid = tid >> 6;
    int l31 = lane & 31, kg = lane >> 5;
    const ushort* xpb = xp + (size_t)b * HW2 * CIN;
    const ushort* asrc[4];
    #pragma unroll
    for (int j = 0; j < 4; j++) {
        int s = (wid * 4 + j) * 64 + lane;
        int r = s >> 3, c8p = s & 7;
        int c8l = c8p ^ (r & 7);
        int hw = hw0 + r;
        int h = hw / W_, w = hw - h * W_;
        asrc[j] = xpb + ((size_t)((h + 1) * W2 + (w + 1))) * CIN + c8l * 8;
    }
    int rB = tid >> 3;
    int cB = (tid & 7) ^ (rB & 7);
    f32x16 acc = {};
    int K = 9 * CIN, nk = K >> 6;
    int tap = 0, cioff = 0;
    for (int kc = 0; kc < nk; kc++) {
        int kg64 = kc << 6;
        int dy = tap / 3, dx = tap - dy * 3;
        int soff = ((dy - 1) * W2 + (dx - 1)) * CIN + cioff;   // wave-uniform
        __syncthreads();
        async16(wB + (size_t)rB * K + kg64 + cB * 8, s_bo + (size_t)tid * 8);
        #pragma unroll
        for (int j = 0; j < 4; j++) {
            int s = (wid * 4 + j) * 64 + lane;
            async16(asrc[j] + soff, s_a + s * 8);
        }
        __syncthreads();
        #pragma unroll
        for (int ks = 0; ks < 4; ks++) {
            int c8l = ks * 2 + kg;
            short8 af = *(const short8*)frag_ptr(s_a, wid * 32 + l31, c8l);
            short8 bf = *(const short8*)frag_ptr(s_bo, l31, c8l);
            acc = mfma16(af, bf, acc);
        }
        cioff += 64;
        if (cioff == CIN) { cioff = 0; tap++; }
    }
    int oc = l31;
    if (oc < 4) {
        float bb = bias[oc];
        int morph = oc >> 1;
        int k3 = (oc & 1) * 2;
        uint2* lt = ltab + ((size_t)oc * B_ + b) * HW;
        #pragma unroll
        for (int reg = 0; reg < 16; reg++) {
            int row = (reg & 3) + 8 * (reg >> 2) + 4 * kg;
            int m = m0 + wid * 32 + row;
            int hw = m - b * HW;
            int h = hw / W_, w = hw - h * W_;
            float bend = tanhf(acc[reg] + bb);
            int i0, i1; float wl;
            if (morph == 0) {
                float ys = fminf(fmaxf((float)h + bend, 0.f), 79.f);
                float y0f = floorf(ys); wl = ys - y0f;
                int y0 = (int)y0f, y1 = min(y0 + 1, 79);
                int xk = min(max(w + k3 - 1, 0), 79);
                i0 = (y0 + 1) * W2 + xk + 1; i1 = (y1 + 1) * W2 + xk + 1;
            } else {
                float xs = fminf(fmaxf((float)w + bend, 0.f), 79.f);
                float x0f = floorf(xs); wl = xs - x0f;
                int x0 = (int)x0f, x1 = min(x0 + 1, 79);
                int yk = min(max(h + k3 - 1, 0), 79);
                i0 = (yk + 1) * W2 + x0 + 1; i1 = (yk + 1) * W2 + x1 + 1;
            }
            lt[hw] = make_uint2((unsigned)i0 | ((unsigned)i1 << 16),
                                __float_as_uint(wl));
        }
    }
}

// ---------------------------------------------------------------------------
// FUSED conv3x3-GEMM + snake-conv-GEMM.  grid (400, OC/128, 3).
// z=0: conv3x3; z=1/2: dsc morph 0/1.  Lerp params from global ltab
// (precomputed in off_gemm) -> LDS exactly 32KB.  launch_bounds (256,4)
// keeps the allocator at its natural 64 VGPR (r12: demanding 5 spilled);
// with 32KB LDS + 64 VGPR the HW can reach 5 blocks/CU on its own.
// ---------------------------------------------------------------------------
__global__ __launch_bounds__(256, 4) void convdsc_kernel(
    const ushort* __restrict__ xp,
    const ushort* __restrict__ wC, const float* __restrict__ biasC,
    ushort* __restrict__ outC,
    const uint2* __restrict__ ltab,
    const ushort* __restrict__ Bwx, const float* __restrict__ biasx,
    ushort* __restrict__ outx,
    const ushort* __restrict__ Bwy, const float* __restrict__ biasy,
    ushort* __restrict__ outy, float* __restrict__ stat, int CIN, int OC) {
    __shared__ ushort s_a[128 * 64];
    __shared__ ushort s_b[128 * 64];
    int tid = threadIdx.x;
    int m0 = xcd_swz400(blockIdx.x) * 128, n0 = blockIdx.y * 128;
    int b = m0 / HW, hw0 = m0 - b * HW;     // 6400 % 128 == 0
    int lane = tid & 63, wid = tid >> 6;
    int l31 = lane & 31, kg = lane >> 5;
    int wm = wid >> 1, wn = wid & 1;

    if (blockIdx.z == 0) {
        // ---------------- conv3x3 path ----------------
        const ushort* xpb = xp + (size_t)b * HW2 * CIN;
        const ushort* asrc[4];
        #pragma unroll
        for (int j = 0; j < 4; j++) {
            int s = (wid * 4 + j) * 64 + lane;
            int r = s >> 3, c8p = s & 7;
            int c8l = c8p ^ (r & 7);
            int hw = hw0 + r;
            int h = hw / W_, w = hw - h * W_;
            asrc[j] = xpb + ((size_t)((h + 1) * W2 + (w + 1))) * CIN + c8l * 8;
        }
        f32x16 acc[2][2] = {};
        int K = 9 * CIN, nk = K >> 6;
        int tap = 0, cioff = 0;
        for (int kc = 0; kc < nk; kc++) {
            int kg64 = kc << 6;
            int dy = tap / 3, dx = tap - dy * 3;
            int soff = ((dy - 1) * W2 + (dx - 1)) * CIN + cioff;   // wave-uniform
            __syncthreads();
            #pragma unroll
            for (int j = 0; j < 4; j++) {
                int s = (wid * 4 + j) * 64 + lane;
                int r = s >> 3, c8p = s & 7;
                int c8l = c8p ^ (r & 7);
                async16(wC + (size_t)(n0 + r) * K + kg64 + c8l * 8, s_b + s * 8);
                async16(asrc[j] + soff, s_a + s * 8);
            }
            __syncthreads();
            #pragma unroll
            for (int ks = 0; ks < 4; ks++) {
                int c8l = ks * 2 + kg;
                short8 af0 = *(const short8*)frag_ptr(s_a, wm * 64 + l31, c8l);
                short8 af1 = *(const short8*)frag_ptr(s_a, wm * 64 + 32 + l31, c8l);
                short8 bf0 = *(const short8*)frag_ptr(s_b, wn * 64 + l31, c8l);
                short8 bf1 = *(const short8*)frag_ptr(s_b, wn * 64 + 32 + l31, c8l);
                acc[0][0] = mfma16(af0, bf0, acc[0][0]);
                acc[0][1] = mfma16(af0, bf1, acc[0][1]);
                acc[1][0] = mfma16(af1, bf0, acc[1][0]);
                acc[1][1] = mfma16(af1, bf1, acc[1][1]);
            }
            cioff += 64;
            if (cioff == CIN) { cioff = 0; tap++; }
        }
        int na = n0 + wn * 64 + l31, nb = na + 32;
        float ba = biasC[na], bb2 = biasC[nb];
        #pragma unroll
        for (int mf = 0; mf < 2; mf++) {
            #pragma unroll
            for (int reg = 0; reg < 16; reg++) {
                int row = (reg & 3) + 8 * (reg >> 2) + 4 * kg;
                int m = m0 + wm * 64 + mf * 32 + row;
                float v0 = acc[mf][0][reg] + ba;
                float v1 = acc[mf][1][reg] + bb2;
                v0 = v0 / (1.f + expf(-v0));
                v1 = v1 / (1.f + expf(-v1));
                outC[(size_t)m * OC + na] = f2bf(v0);
                outC[(size_t)m * OC + nb] = f2bf(v1);
            }
        }
        return;
    }

    // ---------------- dsc path ----------------
    int morph = blockIdx.z - 1;
    const ushort* Bw = morph ? Bwy : Bwx;
    const float* bias = morph ? biasy : biasx;
    ushort* out = morph ? outy : outx;
    float* statm = stat + (size_t)morph * B_ * 256 * 2;
    const ushort* xb = xp + (size_t)b * HW2 * CIN;
    const ushort* asrcC[4];
    #pragma unroll
    for (int j = 0; j < 4; j++) {
        int s = (wid * 4 + j) * 64 + lane;
        int r = s >> 3, c8p = s & 7;
        int c8l = c8p ^ (r & 7);
        int hw = hw0 + r;
        int h = hw / W_, w = hw - h * W_;
        asrcC[j] = xb + ((size_t)((h + 1) * W2 + (w + 1))) * CIN + c8l * 8;
    }
    f32x16 acc[2][2] = {};
    int K = 3 * CIN, nk = K >> 6;
    for (int kc = 0; kc < nk; kc++) {
        int kg64 = kc << 6;
        int k3 = kg64 / CIN;              // uniform per kc (64 | CIN)
        int cioff = kg64 - k3 * CIN;
        __syncthreads();
        #pragma unroll
        for (int j = 0; j < 4; j++) {
            int s = (wid * 4 + j) * 64 + lane;
            int r = s >> 3, c8p = s & 7;
            int c8l = c8p ^ (r & 7);
            async16(Bw + (size_t)(n0 + r) * K + kg64 + c8l * 8, s_b + s * 8);
        }
        if (k3 == 1) {
            // center tap: wl==0, sampled == x[center] -> pure DMA
            #pragma unroll
            for (int j = 0; j < 4; j++) {
                int s = (wid * 4 + j) * 64 + lane;
                async16(asrcC[j] + cioff, s_a + s * 8);
            }
        } else {
            const uint2* ltk = ltab
                + ((size_t)(morph * 2 + (k3 >> 1)) * B_ + b) * HW + hw0;
            #pragma unroll
            for (int i = 0; i < 4; i++) {
                int s = i * 256 + tid;
                int r = s >> 3, c8p = s & 7;
                int c8l = c8p ^ (r & 7);
                int ci = cioff + c8l * 8;
                uint2 rec = ltk[r];
                int i0 = rec.x & 0xFFFF;
                int i1 = rec.x >> 16;
                float wl = __uint_as_float(rec.y);
                uint4 u0 = *(const uint4*)(xb + (size_t)i0 * CIN + ci);
                uint4 u1 = *(const uint4*)(xb + (size_t)i1 * CIN + ci);
                const ushort* p0 = (const ushort*)&u0;
                const ushort* p1 = (const ushort*)&u1;
                uint ov[4];
                #pragma unroll
                for (int j = 0; j < 4; j++) {
                    float a0 = bf2f(p0[2 * j]),     b0 = bf2f(p1[2 * j]);
                    float a1 = bf2f(p0[2 * j + 1]), b1 = bf2f(p1[2 * j + 1]);
                    float r0 = a0 + (b0 - a0) * wl;
                    float r1 = a1 + (b1 - a1) * wl;
                    asm("v_cvt_pk_bf16_f32 %0, %1, %2"
                        : "=v"(ov[j]) : "v"(r0), "v"(r1));
                }
                *(uint4*)(s_a + s * 8) = *(uint4*)ov;
            }
        }
        __syncthreads();
        #pragma unroll
        for (int ks = 0; ks < 4; ks++) {
            int c8l = ks * 2 + kg;
            short8 af0 = *(const short8*)frag_ptr(s_a, wm * 64 + l31, c8l);
            short8 af1 = *(const short8*)frag_ptr(s_a, wm * 64 + 32 + l31, c8l);
            short8 bf0 = *(const short8*)frag_ptr(s_b, wn * 64 + l31, c8l);
            short8 bf1 = *(const short8*)frag_ptr(s_b, wn * 64 + 32 + l31, c8l);
            acc[0][0] = mfma16(af0, bf0, acc[0][0]);
            acc[0][1] = mfma16(af0, bf1, acc[0][1]);
            acc[1][0] = mfma16(af1, bf0, acc[1][0]);
            acc[1][1] = mfma16(af1, bf1, acc[1][1]);
        }
    }
    int na = n0 + wn * 64 + l31, nb = na + 32;
    float ba = bias[na], bb2 = bias[nb];
    float ssum0 = 0.f, ssq0 = 0.f, ssum1 = 0.f, ssq1 = 0.f;
    #pragma unroll
    for (int mf = 0; mf < 2; mf++) {
        #pragma unroll
        for (int reg = 0; reg < 16; reg++) {
            int row = (reg & 3) + 8 * (reg >> 2) + 4 * kg;
            int m = m0 + wm * 64 + mf * 32 + row;
            float v0 = acc[mf][0][reg] + ba;
            float v1 = acc[mf][1][reg] + bb2;
            ssum0 += v0; ssq0 += v0 * v0;
            ssum1 += v1; ssq1 += v1 * v1;
            out[(size_t)m * OC + na] = f2bf(v0);
            out[(size_t)m * OC + nb] = f2bf(v1);
        }
    }
    ssum0 += __shfl_xor(ssum0, 32);
    ssq0  += __shfl_xor(ssq0, 32);
    ssum1 += __shfl_xor(ssum1, 32);
    ssq1  += __shfl_xor(ssq1, 32);
    if (kg == 0) {
        float* st0 = statm + ((size_t)b * OC + na) * 2;
        atomicAdd(st0, ssum0);
        atomicAdd(st0 + 1, ssq0);
        float* st1 = statm + ((size_t)b * OC + nb) * 2;
        atomicAdd(st1, ssum1);
        atomicAdd(st1 + 1, ssq1);
    }
}

// ---------------------------------------------------------------------------
// 128x128 MFMA GEMM over concat-A (3 parts).  Part 0 staged via DMA;
// parts 1/2 staged via VGPR with FUSED GroupNorm scale/shift + ReLU.
// SiLU epilogue (line-complete stores); optional padded output.
// XCD-swizzled m-tiles, 32KB LDS.  grid (400, N/128)
// ---------------------------------------------------------------------------
__global__ __launch_bounds__(256, 4) void gemm128_kernel(
    const ushort* __restrict__ a0, const ushort* __restrict__ a1,
    const ushort* __restrict__ a2, int part_k,
    const ushort* __restrict__ Bw, int K, int N,
    const float* __restrict__ bias,
    const float* __restrict__ scx, const float* __restrict__ shx,
    const float* __restrict__ scy, const float* __restrict__ shy,
    ushort* __restrict__ out, int epi_silu, int out_pad) {
    __shared__ ushort s_a[128 * 64];
    __shared__ ushort s_b[128 * 64];
    int tid = threadIdx.x;
    int m0 = xcd_swz400(blockIdx.x) * 128, n0 = blockIdx.y * 128;
    int b = m0 / HW;                        // uniform (6400 % 128 == 0)
    int lane = tid & 63, wid = tid >> 6;
    int l31 = lane & 31, kg = lane >> 5;
    int wm = wid >> 1, wn = wid & 1;
    f32x16 acc[2][2] = {};
    int nk = K >> 6;
    for (int kc = 0; kc < nk; kc++) {
        int kg64 = kc << 6;
        int part = kg64 / part_k;
        int koff = kg64 - part * part_k;
        __syncthreads();
        #pragma unroll
        for (int j = 0; j < 4; j++) {
            int s = (wid * 4 + j) * 64 + lane;
            int r = s >> 3, c8p = s & 7;
            int c8l = c8p ^ (r & 7);
            async16(Bw + (size_t)(n0 + r) * K + kg64 + c8l * 8, s_b + s * 8);
        }
        if (part == 0) {
            #pragma unroll
            for (int j = 0; j < 4; j++) {
                int s = (wid * 4 + j) * 64 + lane;
                int r = s >> 3, c8p = s & 7;
                int c8l = c8p ^ (r & 7);
                async16(a0 + (size_t)(m0 + r) * part_k + koff + c8l * 8,
                        s_a + s * 8);
            }
        } else {
            const ushort* ap = (part == 1) ? a1 : a2;
            const float* scp = ((part == 1) ? scx : scy) + (size_t)b * part_k;
            const float* shp = ((part == 1) ? shx : shy) + (size_t)b * part_k;
            #pragma unroll
            for (int i = 0; i < 4; i++) {
                int s = i * 256 + tid;
                int r = s >> 3, c8p = s & 7;
                int c8l = c8p ^ (r & 7);
                int ch = koff + c8l * 8;
                uint4 u = *(const uint4*)(ap + (size_t)(m0 + r) * part_k + ch);
                float4 c0 = *(const float4*)(scp + ch);
                float4 c1 = *(const float4*)(scp + ch + 4);
                float4 h0 = *(const float4*)(shp + ch);
                float4 h1 = *(const float4*)(shp + ch + 4);
                const ushort* pv = (const ushort*)&u;
                uint ov[4];
                float r0, r1;
                r0 = fmaxf(bf2f(pv[0]) * c0.x + h0.x, 0.f);
                r1 = fmaxf(bf2f(pv[1]) * c0.y + h0.y, 0.f);
                asm("v_cvt_pk_bf16_f32 %0, %1, %2" : "=v"(ov[0]) : "v"(r0), "v"(r1));
                r0 = fmaxf(bf2f(pv[2]) * c0.z + h0.z, 0.f);
                r1 = fmaxf(bf2f(pv[3]) * c0.w + h0.w, 0.f);
                asm("v_cvt_pk_bf16_f32 %0, %1, %2" : "=v"(ov[1]) : "v"(r0), "v"(r1));
                r0 = fmaxf(bf2f(pv[4]) * c1.x + h1.x, 0.f);
                r1 = fmaxf(bf2f(pv[5]) * c1.y + h1.y, 0.f);
                asm("v_cvt_pk_bf16_f32 %0, %1, %2" : "=v"(ov[2]) : "v"(r0), "v"(r1));
                r0 = fmaxf(bf2f(pv[6]) * c1.z + h1.z, 0.f);
                r1 = fmaxf(bf2f(pv[7]) * c1.w + h1.w, 0.f);
                asm("v_cvt_pk_bf16_f32 %0, %1, %2" : "=v"(ov[3]) : "v"(r0), "v"(r1));
                *(uint4*)(s_a + s * 8) = *(uint4*)ov;
            }
        }
        __syncthreads();
        #pragma unroll
        for (int ks = 0; ks < 4; ks++) {
            int c8l = ks * 2 + kg;
            short8 af0 = *(const short8*)frag_ptr(s_a, wm * 64 + l31, c8l);
            short8 af1 = *(const short8*)frag_ptr(s_a, wm * 64 + 32 + l31, c8l);
            short8 bf0 = *(const short8*)frag_ptr(s_b, wn * 64 + l31, c8l);
            short8 bf1 = *(const short8*)frag_ptr(s_b, wn * 64 + 32 + l31, c8l);
            acc[0][0] = mfma16(af0, bf0, acc[0][0]);
            acc[0][1] = mfma16(af0, bf1, acc[0][1]);
            acc[1][0] = mfma16(af1, bf0, acc[1][0]);
            acc[1][1] = mfma16(af1, bf1, acc[1][1]);
        }
    }
    int na = n0 + wn * 64 + l31, nb = na + 32;
    float ba = bias[na], bb2 = bias[nb];
    #pragma unroll
    for (int mf = 0; mf < 2; mf++) {
        #pragma unroll
        for (int reg = 0; reg < 16; reg++) {
            int row = (reg & 3) + 8 * (reg >> 2) + 4 * kg;
            int m = m0 + wm * 64 + mf * 32 + row;
            float v0 = acc[mf][0][reg] + ba;
            float v1 = acc[mf][1][reg] + bb2;
            if (epi_silu) {
                v0 = v0 / (1.f + expf(-v0));
                v1 = v1 / (1.f + expf(-v1));
            }
            size_t mm = (size_t)m;
            if (out_pad) {
                int bb_ = m / HW, hw = m - bb_ * HW;
                int h = hw / W_, w = hw - h * W_;
                mm = (size_t)bb_ * HW2 + (h + 1) * W2 + w + 1;
            }
            out[mm * N + na] = f2bf(v0);
            out[mm * N + nb] = f2bf(v1);
        }
    }
}

// ---------------------------------------------------------------------------
// GN finalize from fused per-channel sums: grid (ceil(B*C/256), 2)
// ---------------------------------------------------------------------------
__global__ void gn_finalize_kernel(const float* __restrict__ stat,
                                   const float* __restrict__ gx,
                                   const float* __restrict__ bx,
                                   const float* __restrict__ gy,
                                   const float* __restrict__ by,
                                   float* __restrict__ scx, float* __restrict__ shx,
                                   float* __restrict__ scy, float* __restrict__ shy,
                                   int C) {
    int idx = blockIdx.x * 256 + threadIdx.x;
    if (idx >= B_ * C) return;
    int which = blockIdx.y;
    const float* gamma = which ? gy : gx;
    const float* beta  = which ? by : bx;
    float* sc = which ? scy : scx;
    float* sh = which ? shy : shx;
    int b = idx / C, c = idx - b * C;
    const float* st = stat + (size_t)which * B_ * 256 * 2
                    + ((size_t)b * C + (c & ~3)) * 2;
    float s  = st[0] + st[2] + st[4] + st[6];
    float sq = st[1] + st[3] + st[5] + st[7];
    float mean = s / (4.f * HW);
    float var = sq / (4.f * HW) - mean * mean;
    float rs = rsqrtf(var + 1e-5f);
    float scale = rs * gamma[c];
    sc[idx] = scale;
    sh[idx] = beta[c] - mean * scale;
}

// ---------------------------------------------------------------------------
// Host orchestration
// ---------------------------------------------------------------------------
struct BlkBuf {
    ushort *xp, *abuf, *bqx, *bqy, *hout;
    uint2 *ltab;
    float *stat, *scx, *shx, *scy, *shy, *boff;
    ushort *wc, *wdx, *wdy, *wf, *woff;
};

static void run_block(const BlkBuf& B, int CIN, int OC,
                      const float* const* P, int out_pad, hipStream_t stream) {
    dim3 blk(256);
    off_gemm_kernel<<<dim3(B_ * HW / 128), blk, 0, stream>>>(
        B.xp, B.woff, B.boff, B.ltab, CIN);
    convdsc_kernel<<<dim3(400, OC / 128, 3), blk, 0, stream>>>(
        B.xp, B.wc, P[1], B.abuf,
        B.ltab, B.wdx, P[5], B.bqx, B.wdy, P[11], B.bqy, B.stat, CIN, OC);
    int fgrid = (B_ * OC + 255) / 256;
    gn_finalize_kernel<<<dim3(fgrid, 2), blk, 0, stream>>>(
        B.stat, P[6], P[7], P[12], P[13], B.scx, B.shx, B.scy, B.shy, OC);
    gemm128_kernel<<<dim3(400, OC / 128), blk, 0, stream>>>(
        B.abuf, B.bqx, B.bqy, OC, B.wf, 3 * OC, OC, P[15],
        B.scx, B.shx, B.scy, B.shy, B.hout, 1, out_pad);
}

extern "C" void kernel_launch(void* const* d_in, const int* in_sizes, int n_in,
                              void* d_out, int out_size, void* d_ws, size_t ws_size,
                              hipStream_t stream) {
    const float* x = (const float*)d_in[0];
    const float* P1[16];
    const float* P2[16];
    for (int i = 0; i < 16; i++) {
        P1[i] = (const float*)d_in[1 + i];
        P2[i] = (const float*)d_in[17 + i];
    }
    char* base = (char*)d_ws;
    size_t off = 0;
    auto alloc = [&](size_t bytes) -> char* {
        off = (off + 255) & ~(size_t)255;
        char* p = base + off;
        off += bytes;
        return p;
    };
    ushort* xp1  = (ushort*)alloc((size_t)B_ * HW2 * 256 * 2);  // padded block1 input
    ushort* xp2  = (ushort*)alloc((size_t)B_ * HW2 * 128 * 2);  // padded block2 input
    ushort* abuf = (ushort*)alloc((size_t)B_ * HW * 256 * 2);
    ushort* bqx  = (ushort*)alloc((size_t)B_ * HW * 256 * 2);
    ushort* bqy  = (ushort*)alloc((size_t)B_ * HW * 256 * 2);
    uint2*  ltab = (uint2*)alloc((size_t)4 * B_ * HW * 8);   // lerp records
    float*  stat1 = (float*)alloc((size_t)2 * B_ * 256 * 2 * 4);
    float*  stat2 = (float*)alloc((size_t)2 * B_ * 256 * 2 * 4);
    float*  scx  = (float*)alloc(B_ * 256 * 4);
    float*  shx  = (float*)alloc(B_ * 256 * 4);
    float*  scy  = (float*)alloc(B_ * 256 * 4);
    float*  shy  = (float*)alloc(B_ * 256 * 4);
    ushort* wc1  = (ushort*)alloc((size_t)128 * 9 * 256 * 2);
    ushort* wc2  = (ushort*)alloc((size_t)256 * 9 * 128 * 2);
    ushort* wdx1 = (ushort*)alloc((size_t)128 * 3 * 256 * 2);
    ushort* wdy1 = (ushort*)alloc((size_t)128 * 3 * 256 * 2);
    ushort* wdx2 = (ushort*)alloc((size_t)256 * 3 * 128 * 2);
    ushort* wdy2 = (ushort*)alloc((size_t)256 * 3 * 128 * 2);
    ushort* wf1  = (ushort*)alloc((size_t)128 * 384 * 2);
    ushort* wf2  = (ushort*)alloc((size_t)256 * 768 * 2);
    ushort* wo1  = (ushort*)alloc((size_t)32 * 9 * 256 * 2);
    ushort* wo2  = (ushort*)alloc((size_t)32 * 9 * 128 * 2);
    float*  bo1  = (float*)alloc(32 * 4);
    float*  bo2  = (float*)alloc(32 * 4);
    // h2 (block2 dense output, [B][HW][256]) aliases xp1 (dead after block1)
    ushort* h2 = xp1;

    dim3 blk(256);
    // both stat buffers zeroed up-front (no mid-pipeline memset dispatches)
    hipMemsetAsync(stat1, 0, (size_t)2 * B_ * 256 * 2 * 4, stream);
    hipMemsetAsync(stat2, 0, (size_t)2 * B_ * 256 * 2 * 4, stream);
    // zero halos of both padded buffers in one launch
    {
        int total = B_ * 324 * 32 + B_ * 324 * 16;
        halo_zero2_kernel<<<(total + 255) / 256, blk, 0, stream>>>(xp1, xp2);
    }

    // combined weight prep (8 jobs, 1 launch)
    {
        WJobs J;
        const float* srcs[8] = {P1[0], P1[4], P1[10], P1[14],
                                P2[0], P2[4], P2[10], P2[14]};
        ushort* dsts[8] = {wc1, wdx1, wdy1, wf1, wc2, wdx2, wdy2, wf2};
        int cins[8] = {256, 256, 256, 384, 128, 128, 128, 768};
        int ts[8]   = {9, 3, 3, 1, 9, 3, 3, 1};
        int ocs[8]  = {128, 128, 128, 128, 256, 256, 256, 256};
        int acc = 0;
        for (int j = 0; j < 8; j++) {
            J.src[j] = srcs[j]; J.dst[j] = dsts[j];
            J.cin[j] = cins[j]; J.t[j] = ts[j];
            J.start[j] = acc;
            acc += ocs[j] * cins[j] * ts[j];
        }
        J.start[8] = acc;
        wprep_all_kernel<<<(acc + 255) / 256, blk, 0, stream>>>(J);
    }
    wprep_off_kernel<<<(32 * 9 * 256 + 255) / 256, blk, 0, stream>>>(
        P1[2], P1[3], P1[8], P1[9], wo1, bo1, 256);
    wprep_off_kernel<<<(32 * 9 * 128 + 255) / 256, blk, 0, stream>>>(
        P2[2], P2[3], P2[8], P2[9], wo2, bo2, 128);

    transpose_x_kernel<<<dim3(100, 4, B_), blk, 0, stream>>>(x, xp1, 256);

    BlkBuf B1 = {xp1, abuf, bqx, bqy, xp2, ltab, stat1, scx, shx, scy, shy,
                 bo1, wc1, wdx1, wdy1, wf1, wo1};
    run_block(B1, 256, 128, P1, /*out_pad=*/1, stream);

    BlkBuf B2 = {xp2, abuf, bqx, bqy, h2, ltab, stat2, scx, shx, scy, shy,
                 bo2, wc2, wdx2, wdy2, wf2, wo2};
    run_block(B2, 128, 256, P2, /*out_pad=*/0, stream);

    final_add_kernel<<<dim3(100, 4, B_), blk, 0, stream>>>(x, h2, (float*)d_out, 256);
}

// Round 14
// 478.460 us; speedup vs baseline: 1.3117x; 1.0510x over previous
//
#include <hip/hip_runtime.h>
#include <cstddef>

#define B_   8
#define H_   80
#define W_   80
#define HW   6400
#define W2   82
#define HW2  6724   // 82*82 padded plane

typedef __attribute__((ext_vector_type(8)))  short short8;
typedef __attribute__((ext_vector_type(16))) float f32x16;

__device__ __forceinline__ float bf2f(ushort u) {
    return __uint_as_float(((unsigned)u) << 16);
}
__device__ __forceinline__ ushort f2bf(float f) {
    unsigned u = __float_as_uint(f);
    u += 0x7FFF + ((u >> 16) & 1);   // RNE
    return (ushort)(u >> 16);
}
__device__ __forceinline__ f32x16 mfma16(short8 a, short8 b, f32x16 c) {
    return __builtin_amdgcn_mfma_f32_32x32x16_bf16(a, b, c, 0, 0, 0);
}
// async global->LDS, 16B per lane (wave-uniform base + lane*16)
__device__ __forceinline__ void async16(const void* g, void* l) {
    __builtin_amdgcn_global_load_lds(
        (const __attribute__((address_space(1))) unsigned int*)g,
        (__attribute__((address_space(3))) unsigned int*)l, 16, 0, 0);
}
// swizzled fragment address in 64-ushort-stride LDS tile
__device__ __forceinline__ const ushort* frag_ptr(const ushort* sbuf, int row, int c8l) {
    return sbuf + row * 64 + ((c8l ^ (row & 7)) << 3);
}
// XCD-aware bijective blockIdx swizzle for 400-tile m-grids (400 % 8 == 0).
// XCD = linear_wg_id % 8; y/z strides are multiples of 400 (≡0 mod 8), so
// each XCD gets one contiguous 50-tile chunk (= one batch image; 3.44MB
// padded plane fits 4MB XCD L2).  [r9: FETCH 101.8->13.0 MB measured]
__device__ __forceinline__ int xcd_swz400(int bid) {
    return (bid & 7) * 50 + (bid >> 3);
}

// ---------------------------------------------------------------------------
// Zero the 1-px halos of BOTH padded NHWC buffers in one launch.
// ---------------------------------------------------------------------------
__global__ __launch_bounds__(256) void halo_zero2_kernel(
    ushort* __restrict__ xp1, ushort* __restrict__ xp2) {
    int idx = blockIdx.x * 256 + threadIdx.x;
    const int n1 = B_ * 324 * 32;   // C=256 -> 32 slots
    const int n2 = B_ * 324 * 16;   // C=128 -> 16 slots
    ushort* xp; int C, slots, i;
    if (idx < n1) { xp = xp1; C = 256; slots = 32; i = idx; }
    else if (idx < n1 + n2) { xp = xp2; C = 128; slots = 16; i = idx - n1; }
    else return;
    int sl = i % slots;
    int t = i / slots;
    int p = t % 324;
    int b = t / 324;
    int h, w;
    if (p < 164) { h = (p < 82) ? 0 : 81; w = p % 82; }
    else { int q = p - 164; w = (q < 80) ? 0 : 81; h = 1 + (q % 80); }
    *(uint4*)(xp + ((size_t)(b * HW2 + h * W2 + w)) * C + sl * 8) =
        make_uint4(0, 0, 0, 0);
}

// ---------------------------------------------------------------------------
// x fp32 NCHW -> xp bf16 padded NHWC [B][82][82][C].  grid (HW/64, C/64, B)
// ---------------------------------------------------------------------------
__global__ __launch_bounds__(256) void transpose_x_kernel(
    const float* __restrict__ x, ushort* __restrict__ xp, int C) {
    __shared__ float s[64][65];
    int hw0 = blockIdx.x * 64, c0 = blockIdx.y * 64, b = blockIdx.z;
    int t = threadIdx.x;
    int hl = t & 63, cq = t >> 6;
    #pragma unroll
    for (int i = 0; i < 16; i++) {
        int cl = cq * 16 + i;
        s[cl][hl] = x[((size_t)(b * C + c0 + cl)) * HW + hw0 + hl];
    }
    __syncthreads();
    int cl = t & 63, hq = t >> 6;
    #pragma unroll
    for (int i = 0; i < 16; i++) {
        int hl2 = hq * 16 + i;
        int hw = hw0 + hl2;
        int h = hw / W_, w = hw - h * W_;
        xp[((size_t)(b * HW2 + (h + 1) * W2 + w + 1)) * C + c0 + cl] = f2bf(s[cl][hl2]);
    }
}

// ---------------------------------------------------------------------------
// final: d_out[b][c][hw] = x[b][c][hw] + h2[b][hw][c]   (h2 dense NHWC)
// ---------------------------------------------------------------------------
__global__ __launch_bounds__(256) void final_add_kernel(
    const float* __restrict__ x, const ushort* __restrict__ h2,
    float* __restrict__ out, int C) {
    __shared__ float s[64][65];
    int hw0 = blockIdx.x * 64, c0 = blockIdx.y * 64, b = blockIdx.z;
    int t = threadIdx.x;
    int cl = t & 63, hq = t >> 6;
    #pragma unroll
    for (int i = 0; i < 16; i++) {
        int hl = hq * 16 + i;
        s[cl][hl] = bf2f(h2[((size_t)(b * HW + hw0 + hl)) * C + c0 + cl]);
    }
    __syncthreads();
    int hl = t & 63, cq = t >> 6;
    #pragma unroll
    for (int i = 0; i < 16; i++) {
        int cl2 = cq * 16 + i;
        size_t o = ((size_t)(b * C + c0 + cl2)) * HW + hw0 + hl;
        out[o] = x[o] + s[cl2][hl];
    }
}

// ---------------------------------------------------------------------------
// Combined weight prep: 8 jobs fp32 [OC][CIN][T] -> bf16 [OC][T][CIN]
// ---------------------------------------------------------------------------
struct WJobs {
    const float* src[8];
    ushort* dst[8];
    int cin[8], t[8];
    int start[9];
};

__global__ __launch_bounds__(256) void wprep_all_kernel(WJobs J) {
    int idx = blockIdx.x * 256 + threadIdx.x;
    if (idx >= J.start[8]) return;
    int j = 0;
    #pragma unroll
    for (int k = 1; k < 8; k++) if (idx >= J.start[k]) j = k;
    int i = idx - J.start[j];
    int CIN = J.cin[j], T = J.t[j];
    int oc = i / (CIN * T);
    int r = i - oc * CIN * T;
    int ci = r / T, t_ = r - ci * T;
    J.dst[j][((size_t)oc * T + t_) * CIN + ci] = f2bf(J.src[j][i]);
}

// ---------------------------------------------------------------------------
// Offset weight prep: pack 4 wanted channels (+28 zero pads) into [32][9][CIN]
// ---------------------------------------------------------------------------
__global__ void wprep_off_kernel(const float* __restrict__ wx_,
                                 const float* __restrict__ bx_,
                                 const float* __restrict__ wy_,
                                 const float* __restrict__ by_,
                                 ushort* __restrict__ dst,
                                 float* __restrict__ bdst, int CIN) {
    int idx = blockIdx.x * 256 + threadIdx.x;
    if (idx < 4) {
        const int chs[4] = {0, 2, 3, 5};
        bdst[idx] = (idx < 2) ? bx_[chs[idx]] : by_[chs[idx]];
    }
    if (idx >= 32 * 9 * CIN) return;
    int oc = idx / (9 * CIN);
    int r = idx - oc * 9 * CIN;
    int tap = r / CIN, ci = r - tap * CIN;
    float v = 0.f;
    if (oc < 4) {
        const int chs[4] = {0, 2, 3, 5};
        const float* src = (oc < 2) ? wx_ : wy_;
        v = src[((size_t)chs[oc] * CIN + ci) * 9 + tap];
    }
    dst[idx] = f2bf(v);
}

// ---------------------------------------------------------------------------
// Offset conv as shifted-row implicit GEMM, N=32 (4 real oc), tanh epilogue.
// All-DMA staging from padded NHWC, LDS 20KB.  grid (B*HW/128)
// ---------------------------------------------------------------------------
__global__ __launch_bounds__(256, 4) void off_gemm_kernel(
    const ushort* __restrict__ xp, const ushort* __restrict__ wB,
    const float* __restrict__ bias, float* __restrict__ off4, int CIN) {
    __shared__ ushort s_a[128 * 64];
    __shared__ ushort s_bo[32 * 64];
    int tid = threadIdx.x;
    int m0 = xcd_swz400(blockIdx.x) * 128;
    int b = m0 / HW, hw0 = m0 - b * HW;
    int lane = tid & 63, wid = tid >> 6;
    int l31 = lane & 31, kg = lane >> 5;
    const ushort* xpb = xp + (size_t)b * HW2 * CIN;
    const ushort* asrc[4];
    #pragma unroll
    for (int j = 0; j < 4; j++) {
        int s = (wid * 4 + j) * 64 + lane;
        int r = s >> 3, c8p = s & 7;
        int c8l = c8p ^ (r & 7);
        int hw = hw0 + r;
        int h = hw / W_, w = hw - h * W_;
        asrc[j] = xpb + ((size_t)((h + 1) * W2 + (w + 1))) * CIN + c8l * 8;
    }
    int rB = tid >> 3;
    int cB = (tid & 7) ^ (rB & 7);
    f32x16 acc = {};
    int K = 9 * CIN, nk = K >> 6;
    int tap = 0, cioff = 0;
    for (int kc = 0; kc < nk; kc++) {
        int kg64 = kc << 6;
        int dy = tap / 3, dx = tap - dy * 3;
        int soff = ((dy - 1) * W2 + (dx - 1)) * CIN + cioff;   // wave-uniform
        __syncthreads();
        async16(wB + (size_t)rB * K + kg64 + cB * 8, s_bo + (size_t)tid * 8);
        #pragma unroll
        for (int j = 0; j < 4; j++) {
            int s = (wid * 4 + j) * 64 + lane;
            async16(asrc[j] + soff, s_a + s * 8);
        }
        __syncthreads();
        #pragma unroll
        for (int ks = 0; ks < 4; ks++) {
            int c8l = ks * 2 + kg;
            short8 af = *(const short8*)frag_ptr(s_a, wid * 32 + l31, c8l);
            short8 bf = *(const short8*)frag_ptr(s_bo, l31, c8l);
            acc = mfma16(af, bf, acc);
        }
        cioff += 64;
        if (cioff == CIN) { cioff = 0; tap++; }
    }
    int oc = l31;
    if (oc < 4) {
        float bb = bias[oc];
        #pragma unroll
        for (int reg = 0; reg < 16; reg++) {
            int row = (reg & 3) + 8 * (reg >> 2) + 4 * kg;
            int m = m0 + wid * 32 + row;
            int hw = m - b * HW;
            off4[((size_t)b * 4 + oc) * HW + hw] = tanhf(acc[reg] + bb);
        }
    }
}

// ---------------------------------------------------------------------------
// FUSED conv3x3-GEMM + snake-conv-GEMM.  grid (400, OC/128, 3).
// z=0: conv3x3; z=1/2: dsc morph 0/1.  XCD-swizzled m-tiles (one image/XCD).
// Epilogue stores both nf-halves adjacently (full 128B line per row).
// ---------------------------------------------------------------------------
__global__ __launch_bounds__(256, 4) void convdsc_kernel(
    const ushort* __restrict__ xp,
    const ushort* __restrict__ wC, const float* __restrict__ biasC,
    ushort* __restrict__ outC,
    const float* __restrict__ off4,
    const ushort* __restrict__ Bwx, const float* __restrict__ biasx,
    ushort* __restrict__ outx,
    const ushort* __restrict__ Bwy, const float* __restrict__ biasy,
    ushort* __restrict__ outy, float* __restrict__ stat, int CIN, int OC) {
    __shared__ ushort s_a[128 * 64];
    __shared__ ushort s_b[128 * 64];
    __shared__ int   s_i0[3][128];
    __shared__ int   s_i1[3][128];
    __shared__ float s_wl[3][128];
    int tid = threadIdx.x;
    int m0 = xcd_swz400(blockIdx.x) * 128, n0 = blockIdx.y * 128;
    int b = m0 / HW, hw0 = m0 - b * HW;     // 6400 % 128 == 0
    int lane = tid & 63, wid = tid >> 6;
    int l31 = lane & 31, kg = lane >> 5;
    int wm = wid >> 1, wn = wid & 1;

    if (blockIdx.z == 0) {
        // ---------------- conv3x3 path ----------------
        const ushort* xpb = xp + (size_t)b * HW2 * CIN;
        const ushort* asrc[4];
        #pragma unroll
        for (int j = 0; j < 4; j++) {
            int s = (wid * 4 + j) * 64 + lane;
            int r = s >> 3, c8p = s & 7;
            int c8l = c8p ^ (r & 7);
            int hw = hw0 + r;
            int h = hw / W_, w = hw - h * W_;
            asrc[j] = xpb + ((size_t)((h + 1) * W2 + (w + 1))) * CIN + c8l * 8;
        }
        f32x16 acc[2][2] = {};
        int K = 9 * CIN, nk = K >> 6;
        int tap = 0, cioff = 0;
        for (int kc = 0; kc < nk; kc++) {
            int kg64 = kc << 6;
            int dy = tap / 3, dx = tap - dy * 3;
            int soff = ((dy - 1) * W2 + (dx - 1)) * CIN + cioff;   // wave-uniform
            __syncthreads();
            #pragma unroll
            for (int j = 0; j < 4; j++) {
                int s = (wid * 4 + j) * 64 + lane;
                int r = s >> 3, c8p = s & 7;
                int c8l = c8p ^ (r & 7);
                async16(wC + (size_t)(n0 + r) * K + kg64 + c8l * 8, s_b + s * 8);
                async16(asrc[j] + soff, s_a + s * 8);
            }
            __syncthreads();
            #pragma unroll
            for (int ks = 0; ks < 4; ks++) {
                int c8l = ks * 2 + kg;
                short8 af0 = *(const short8*)frag_ptr(s_a, wm * 64 + l31, c8l);
                short8 af1 = *(const short8*)frag_ptr(s_a, wm * 64 + 32 + l31, c8l);
                short8 bf0 = *(const short8*)frag_ptr(s_b, wn * 64 + l31, c8l);
                short8 bf1 = *(const short8*)frag_ptr(s_b, wn * 64 + 32 + l31, c8l);
                acc[0][0] = mfma16(af0, bf0, acc[0][0]);
                acc[0][1] = mfma16(af0, bf1, acc[0][1]);
                acc[1][0] = mfma16(af1, bf0, acc[1][0]);
                acc[1][1] = mfma16(af1, bf1, acc[1][1]);
            }
            cioff += 64;
            if (cioff == CIN) { cioff = 0; tap++; }
        }
        int na = n0 + wn * 64 + l31, nb = na + 32;
        float ba = biasC[na], bb2 = biasC[nb];
        #pragma unroll
        for (int mf = 0; mf < 2; mf++) {
            #pragma unroll
            for (int reg = 0; reg < 16; reg++) {
                int row = (reg & 3) + 8 * (reg >> 2) + 4 * kg;
                int m = m0 + wm * 64 + mf * 32 + row;
                float v0 = acc[mf][0][reg] + ba;
                float v1 = acc[mf][1][reg] + bb2;
                v0 = v0 / (1.f + expf(-v0));
                v1 = v1 / (1.f + expf(-v1));
                outC[(size_t)m * OC + na] = f2bf(v0);
                outC[(size_t)m * OC + nb] = f2bf(v1);
            }
        }
        return;
    }

    // ---------------- dsc path ----------------
    int morph = blockIdx.z - 1;
    const ushort* Bw = morph ? Bwy : Bwx;
    const float* bias = morph ? biasy : biasx;
    ushort* out = morph ? outy : outx;
    float* statm = stat + (size_t)morph * B_ * 256 * 2;
    for (int u = tid; u < 384; u += 256) {
        int k3 = u >> 7, r = u & 127;
        int hw = hw0 + r;
        int h = hw / W_, w = hw - h * W_;
        float bend = 0.f;
        if (k3 != 1) {
            int mp = (morph ? 2 : 0) + (k3 >> 1);
            bend = off4[((size_t)b * 4 + mp) * HW + hw];
        }
        int i0, i1; float wl;
        if (morph == 0) {
            float ys = fminf(fmaxf((float)h + bend, 0.f), 79.f);
            float y0f = floorf(ys); wl = ys - y0f;
            int y0 = (int)y0f, y1 = min(y0 + 1, 79);
            int xk = min(max(w + k3 - 1, 0), 79);
            i0 = (y0 + 1) * W2 + xk + 1; i1 = (y1 + 1) * W2 + xk + 1;
        } else {
            float xs = fminf(fmaxf((float)w + bend, 0.f), 79.f);
            float x0f = floorf(xs); wl = xs - x0f;
            int x0 = (int)x0f, x1 = min(x0 + 1, 79);
            int yk = min(max(h + k3 - 1, 0), 79);
            i0 = (yk + 1) * W2 + x0 + 1; i1 = (yk + 1) * W2 + x1 + 1;
        }
        s_i0[k3][r] = i0; s_i1[k3][r] = i1; s_wl[k3][r] = wl;
    }
    const ushort* xb = xp + (size_t)b * HW2 * CIN;
    const ushort* asrcC[4];
    #pragma unroll
    for (int j = 0; j < 4; j++) {
        int s = (wid * 4 + j) * 64 + lane;
        int r = s >> 3, c8p = s & 7;
        int c8l = c8p ^ (r & 7);
        int hw = hw0 + r;
        int h = hw / W_, w = hw - h * W_;
        asrcC[j] = xb + ((size_t)((h + 1) * W2 + (w + 1))) * CIN + c8l * 8;
    }
    f32x16 acc[2][2] = {};
    int K = 3 * CIN, nk = K >> 6;
    for (int kc = 0; kc < nk; kc++) {
        int kg64 = kc << 6;
        int k3 = kg64 / CIN;              // uniform per kc (64 | CIN)
        int cioff = kg64 - k3 * CIN;
        __syncthreads();
        #pragma unroll
        for (int j = 0; j < 4; j++) {
            int s = (wid * 4 + j) * 64 + lane;
            int r = s >> 3, c8p = s & 7;
            int c8l = c8p ^ (r & 7);
            async16(Bw + (size_t)(n0 + r) * K + kg64 + c8l * 8, s_b + s * 8);
        }
        if (k3 == 1) {
            // center tap: wl==0, sampled == x[center] -> pure DMA
            #pragma unroll
            for (int j = 0; j < 4; j++) {
                int s = (wid * 4 + j) * 64 + lane;
                async16(asrcC[j] + cioff, s_a + s * 8);
            }
        } else {
            #pragma unroll
            for (int i = 0; i < 4; i++) {
                int s = i * 256 + tid;
                int r = s >> 3, c8p = s & 7;
                int c8l = c8p ^ (r & 7);
                int ci = cioff + c8l * 8;
                float wl = s_wl[k3][r];
                uint4 u0 = *(const uint4*)(xb + (size_t)s_i0[k3][r] * CIN + ci);
                uint4 u1 = *(const uint4*)(xb + (size_t)s_i1[k3][r] * CIN + ci);
                const ushort* p0 = (const ushort*)&u0;
                const ushort* p1 = (const ushort*)&u1;
                uint ov[4];
                #pragma unroll
                for (int j = 0; j < 4; j++) {
                    float a0 = bf2f(p0[2 * j]),     b0 = bf2f(p1[2 * j]);
                    float a1 = bf2f(p0[2 * j + 1]), b1 = bf2f(p1[2 * j + 1]);
                    float r0 = a0 + (b0 - a0) * wl;
                    float r1 = a1 + (b1 - a1) * wl;
                    asm("v_cvt_pk_bf16_f32 %0, %1, %2"
                        : "=v"(ov[j]) : "v"(r0), "v"(r1));
                }
                *(uint4*)(s_a + s * 8) = *(uint4*)ov;
            }
        }
        __syncthreads();
        #pragma unroll
        for (int ks = 0; ks < 4; ks++) {
            int c8l = ks * 2 + kg;
            short8 af0 = *(const short8*)frag_ptr(s_a, wm * 64 + l31, c8l);
            short8 af1 = *(const short8*)frag_ptr(s_a, wm * 64 + 32 + l31, c8l);
            short8 bf0 = *(const short8*)frag_ptr(s_b, wn * 64 + l31, c8l);
            short8 bf1 = *(const short8*)frag_ptr(s_b, wn * 64 + 32 + l31, c8l);
            acc[0][0] = mfma16(af0, bf0, acc[0][0]);
            acc[0][1] = mfma16(af0, bf1, acc[0][1]);
            acc[1][0] = mfma16(af1, bf0, acc[1][0]);
            acc[1][1] = mfma16(af1, bf1, acc[1][1]);
        }
    }
    int na = n0 + wn * 64 + l31, nb = na + 32;
    float ba = bias[na], bb2 = bias[nb];
    float ssum0 = 0.f, ssq0 = 0.f, ssum1 = 0.f, ssq1 = 0.f;
    #pragma unroll
    for (int mf = 0; mf < 2; mf++) {
        #pragma unroll
        for (int reg = 0; reg < 16; reg++) {
            int row = (reg & 3) + 8 * (reg >> 2) + 4 * kg;
            int m = m0 + wm * 64 + mf * 32 + row;
            float v0 = acc[mf][0][reg] + ba;
            float v1 = acc[mf][1][reg] + bb2;
            ssum0 += v0; ssq0 += v0 * v0;
            ssum1 += v1; ssq1 += v1 * v1;
            out[(size_t)m * OC + na] = f2bf(v0);
            out[(size_t)m * OC + nb] = f2bf(v1);
        }
    }
    ssum0 += __shfl_xor(ssum0, 32);
    ssq0  += __shfl_xor(ssq0, 32);
    ssum1 += __shfl_xor(ssum1, 32);
    ssq1  += __shfl_xor(ssq1, 32);
    if (kg == 0) {
        float* st0 = statm + ((size_t)b * OC + na) * 2;
        atomicAdd(st0, ssum0);
        atomicAdd(st0 + 1, ssq0);
        float* st1 = statm + ((size_t)b * OC + nb) * 2;
        atomicAdd(st1, ssum1);
        atomicAdd(st1 + 1, ssq1);
    }
}

// ---------------------------------------------------------------------------
// 128x128 MFMA GEMM over concat-A (3 parts).  Part 0 staged via DMA;
// parts 1/2 staged via VGPR with FUSED GroupNorm scale/shift + ReLU.
// SiLU epilogue (line-complete stores); optional padded output.
// XCD-swizzled m-tiles.  grid (400, N/128)
// ---------------------------------------------------------------------------
__global__ __launch_bounds__(256, 4) void gemm128_kernel(
    const ushort* __restrict__ a0, const ushort* __restrict__ a1,
    const ushort* __restrict__ a2, int part_k,
    const ushort* __restrict__ Bw, int K, int N,
    const float* __restrict__ bias,
    const float* __restrict__ scx, const float* __restrict__ shx,
    const float* __restrict__ scy, const float* __restrict__ shy,
    ushort* __restrict__ out, int epi_silu, int out_pad) {
    __shared__ ushort s_a[128 * 64];
    __shared__ ushort s_b[128 * 64];
    int tid = threadIdx.x;
    int m0 = xcd_swz400(blockIdx.x) * 128, n0 = blockIdx.y * 128;
    int b = m0 / HW;                        // uniform (6400 % 128 == 0)
    int lane = tid & 63, wid = tid >> 6;
    int l31 = lane & 31, kg = lane >> 5;
    int wm = wid >> 1, wn = wid & 1;
    f32x16 acc[2][2] = {};
    int nk = K >> 6;
    for (int kc = 0; kc < nk; kc++) {
        int kg64 = kc << 6;
        int part = kg64 / part_k;
        int koff = kg64 - part * part_k;
        __syncthreads();
        #pragma unroll
        for (int j = 0; j < 4; j++) {
            int s = (wid * 4 + j) * 64 + lane;
            int r = s >> 3, c8p = s & 7;
            int c8l = c8p ^ (r & 7);
            async16(Bw + (size_t)(n0 + r) * K + kg64 + c8l * 8, s_b + s * 8);
        }
        if (part == 0) {
            #pragma unroll
            for (int j = 0; j < 4; j++) {
                int s = (wid * 4 + j) * 64 + lane;
                int r = s >> 3, c8p = s & 7;
                int c8l = c8p ^ (r & 7);
                async16(a0 + (size_t)(m0 + r) * part_k + koff + c8l * 8,
                        s_a + s * 8);
            }
        } else {
            const ushort* ap = (part == 1) ? a1 : a2;
            const float* scp = ((part == 1) ? scx : scy) + (size_t)b * part_k;
            const float* shp = ((part == 1) ? shx : shy) + (size_t)b * part_k;
            #pragma unroll
            for (int i = 0; i < 4; i++) {
                int s = i * 256 + tid;
                int r = s >> 3, c8p = s & 7;
                int c8l = c8p ^ (r & 7);
                int ch = koff + c8l * 8;
                uint4 u = *(const uint4*)(ap + (size_t)(m0 + r) * part_k + ch);
                float4 c0 = *(const float4*)(scp + ch);
                float4 c1 = *(const float4*)(scp + ch + 4);
                float4 h0 = *(const float4*)(shp + ch);
                float4 h1 = *(const float4*)(shp + ch + 4);
                const ushort* pv = (const ushort*)&u;
                uint ov[4];
                float r0, r1;
                r0 = fmaxf(bf2f(pv[0]) * c0.x + h0.x, 0.f);
                r1 = fmaxf(bf2f(pv[1]) * c0.y + h0.y, 0.f);
                asm("v_cvt_pk_bf16_f32 %0, %1, %2" : "=v"(ov[0]) : "v"(r0), "v"(r1));
                r0 = fmaxf(bf2f(pv[2]) * c0.z + h0.z, 0.f);
                r1 = fmaxf(bf2f(pv[3]) * c0.w + h0.w, 0.f);
                asm("v_cvt_pk_bf16_f32 %0, %1, %2" : "=v"(ov[1]) : "v"(r0), "v"(r1));
                r0 = fmaxf(bf2f(pv[4]) * c1.x + h1.x, 0.f);
                r1 = fmaxf(bf2f(pv[5]) * c1.y + h1.y, 0.f);
                asm("v_cvt_pk_bf16_f32 %0, %1, %2" : "=v"(ov[2]) : "v"(r0), "v"(r1));
                r0 = fmaxf(bf2f(pv[6]) * c1.z + h1.z, 0.f);
                r1 = fmaxf(bf2f(pv[7]) * c1.w + h1.w, 0.f);
                asm("v_cvt_pk_bf16_f32 %0, %1, %2" : "=v"(ov[3]) : "v"(r0), "v"(r1));
                *(uint4*)(s_a + s * 8) = *(uint4*)ov;
            }
        }
        __syncthreads();
        #pragma unroll
        for (int ks = 0; ks < 4; ks++) {
            int c8l = ks * 2 + kg;
            short8 af0 = *(const short8*)frag_ptr(s_a, wm * 64 + l31, c8l);
            short8 af1 = *(const short8*)frag_ptr(s_a, wm * 64 + 32 + l31, c8l);
            short8 bf0 = *(const short8*)frag_ptr(s_b, wn * 64 + l31, c8l);
            short8 bf1 = *(const short8*)frag_ptr(s_b, wn * 64 + 32 + l31, c8l);
            acc[0][0] = mfma16(af0, bf0, acc[0][0]);
            acc[0][1] = mfma16(af0, bf1, acc[0][1]);
            acc[1][0] = mfma16(af1, bf0, acc[1][0]);
            acc[1][1] = mfma16(af1, bf1, acc[1][1]);
        }
    }
    int na = n0 + wn * 64 + l31, nb = na + 32;
    float ba = bias[na], bb2 = bias[nb];
    #pragma unroll
    for (int mf = 0; mf < 2; mf++) {
        #pragma unroll
        for (int reg = 0; reg < 16; reg++) {
            int row = (reg & 3) + 8 * (reg >> 2) + 4 * kg;
            int m = m0 + wm * 64 + mf * 32 + row;
            float v0 = acc[mf][0][reg] + ba;
            float v1 = acc[mf][1][reg] + bb2;
            if (epi_silu) {
                v0 = v0 / (1.f + expf(-v0));
                v1 = v1 / (1.f + expf(-v1));
            }
            size_t mm = (size_t)m;
            if (out_pad) {
                int bb_ = m / HW, hw = m - bb_ * HW;
                int h = hw / W_, w = hw - h * W_;
                mm = (size_t)bb_ * HW2 + (h + 1) * W2 + w + 1;
            }
            out[mm * N + na] = f2bf(v0);
            out[mm * N + nb] = f2bf(v1);
        }
    }
}

// ---------------------------------------------------------------------------
// GN finalize from fused per-channel sums: grid (ceil(B*C/256), 2)
// ---------------------------------------------------------------------------
__global__ void gn_finalize_kernel(const float* __restrict__ stat,
                                   const float* __restrict__ gx,
                                   const float* __restrict__ bx,
                                   const float* __restrict__ gy,
                                   const float* __restrict__ by,
                                   float* __restrict__ scx, float* __restrict__ shx,
                                   float* __restrict__ scy, float* __restrict__ shy,
                                   int C) {
    int idx = blockIdx.x * 256 + threadIdx.x;
    if (idx >= B_ * C) return;
    int which = blockIdx.y;
    const float* gamma = which ? gy : gx;
    const float* beta  = which ? by : bx;
    float* sc = which ? scy : scx;
    float* sh = which ? shy : shx;
    int b = idx / C, c = idx - b * C;
    const float* st = stat + (size_t)which * B_ * 256 * 2
                    + ((size_t)b * C + (c & ~3)) * 2;
    float s  = st[0] + st[2] + st[4] + st[6];
    float sq = st[1] + st[3] + st[5] + st[7];
    float mean = s / (4.f * HW);
    float var = sq / (4.f * HW) - mean * mean;
    float rs = rsqrtf(var + 1e-5f);
    float scale = rs * gamma[c];
    sc[idx] = scale;
    sh[idx] = beta[c] - mean * scale;
}

// ---------------------------------------------------------------------------
// Host orchestration
// ---------------------------------------------------------------------------
struct BlkBuf {
    ushort *xp, *abuf, *bqx, *bqy, *hout;
    float *off4, *stat, *scx, *shx, *scy, *shy, *boff;
    ushort *wc, *wdx, *wdy, *wf, *woff;
};

static void run_block(const BlkBuf& B, int CIN, int OC,
                      const float* const* P, int out_pad, hipStream_t stream) {
    dim3 blk(256);
    off_gemm_kernel<<<dim3(B_ * HW / 128), blk, 0, stream>>>(
        B.xp, B.woff, B.boff, B.off4, CIN);
    convdsc_kernel<<<dim3(400, OC / 128, 3), blk, 0, stream>>>(
        B.xp, B.wc, P[1], B.abuf,
        B.off4, B.wdx, P[5], B.bqx, B.wdy, P[11], B.bqy, B.stat, CIN, OC);
    int fgrid = (B_ * OC + 255) / 256;
    gn_finalize_kernel<<<dim3(fgrid, 2), blk, 0, stream>>>(
        B.stat, P[6], P[7], P[12], P[13], B.scx, B.shx, B.scy, B.shy, OC);
    gemm128_kernel<<<dim3(400, OC / 128), blk, 0, stream>>>(
        B.abuf, B.bqx, B.bqy, OC, B.wf, 3 * OC, OC, P[15],
        B.scx, B.shx, B.scy, B.shy, B.hout, 1, out_pad);
}

extern "C" void kernel_launch(void* const* d_in, const int* in_sizes, int n_in,
                              void* d_out, int out_size, void* d_ws, size_t ws_size,
                              hipStream_t stream) {
    const float* x = (const float*)d_in[0];
    const float* P1[16];
    const float* P2[16];
    for (int i = 0; i < 16; i++) {
        P1[i] = (const float*)d_in[1 + i];
        P2[i] = (const float*)d_in[17 + i];
    }
    char* base = (char*)d_ws;
    size_t off = 0;
    auto alloc = [&](size_t bytes) -> char* {
        off = (off + 255) & ~(size_t)255;
        char* p = base + off;
        off += bytes;
        return p;
    };
    ushort* xp1  = (ushort*)alloc((size_t)B_ * HW2 * 256 * 2);  // padded block1 input
    ushort* xp2  = (ushort*)alloc((size_t)B_ * HW2 * 128 * 2);  // padded block2 input
    ushort* abuf = (ushort*)alloc((size_t)B_ * HW * 256 * 2);
    ushort* bqx  = (ushort*)alloc((size_t)B_ * HW * 256 * 2);
    ushort* bqy  = (ushort*)alloc((size_t)B_ * HW * 256 * 2);
    float*  off4 = (float*)alloc((size_t)B_ * 4 * HW * 4);
    float*  stat1 = (float*)alloc((size_t)2 * B_ * 256 * 2 * 4);
    float*  stat2 = (float*)alloc((size_t)2 * B_ * 256 * 2 * 4);
    float*  scx  = (float*)alloc(B_ * 256 * 4);
    float*  shx  = (float*)alloc(B_ * 256 * 4);
    float*  scy  = (float*)alloc(B_ * 256 * 4);
    float*  shy  = (float*)alloc(B_ * 256 * 4);
    ushort* wc1  = (ushort*)alloc((size_t)128 * 9 * 256 * 2);
    ushort* wc2  = (ushort*)alloc((size_t)256 * 9 * 128 * 2);
    ushort* wdx1 = (ushort*)alloc((size_t)128 * 3 * 256 * 2);
    ushort* wdy1 = (ushort*)alloc((size_t)128 * 3 * 256 * 2);
    ushort* wdx2 = (ushort*)alloc((size_t)256 * 3 * 128 * 2);
    ushort* wdy2 = (ushort*)alloc((size_t)256 * 3 * 128 * 2);
    ushort* wf1  = (ushort*)alloc((size_t)128 * 384 * 2);
    ushort* wf2  = (ushort*)alloc((size_t)256 * 768 * 2);
    ushort* wo1  = (ushort*)alloc((size_t)32 * 9 * 256 * 2);
    ushort* wo2  = (ushort*)alloc((size_t)32 * 9 * 128 * 2);
    float*  bo1  = (float*)alloc(32 * 4);
    float*  bo2  = (float*)alloc(32 * 4);
    // h2 (block2 dense output, [B][HW][256]) aliases xp1 (dead after block1)
    ushort* h2 = xp1;

    dim3 blk(256);
    // both stat buffers zeroed up-front (no mid-pipeline memset dispatches)
    hipMemsetAsync(stat1, 0, (size_t)2 * B_ * 256 * 2 * 4, stream);
    hipMemsetAsync(stat2, 0, (size_t)2 * B_ * 256 * 2 * 4, stream);
    // zero halos of both padded buffers in one launch
    {
        int total = B_ * 324 * 32 + B_ * 324 * 16;
        halo_zero2_kernel<<<(total + 255) / 256, blk, 0, stream>>>(xp1, xp2);
    }

    // combined weight prep (8 jobs, 1 launch)
    {
        WJobs J;
        const float* srcs[8] = {P1[0], P1[4], P1[10], P1[14],
                                P2[0], P2[4], P2[10], P2[14]};
        ushort* dsts[8] = {wc1, wdx1, wdy1, wf1, wc2, wdx2, wdy2, wf2};
        int cins[8] = {256, 256, 256, 384, 128, 128, 128, 768};
        int ts[8]   = {9, 3, 3, 1, 9, 3, 3, 1};
        int ocs[8]  = {128, 128, 128, 128, 256, 256, 256, 256};
        int acc = 0;
        for (int j = 0; j < 8; j++) {
            J.src[j] = srcs[j]; J.dst[j] = dsts[j];
            J.cin[j] = cins[j]; J.t[j] = ts[j];
            J.start[j] = acc;
            acc += ocs[j] * cins[j] * ts[j];
        }
        J.start[8] = acc;
        wprep_all_kernel<<<(acc + 255) / 256, blk, 0, stream>>>(J);
    }
    wprep_off_kernel<<<(32 * 9 * 256 + 255) / 256, blk, 0, stream>>>(
        P1[2], P1[3], P1[8], P1[9], wo1, bo1, 256);
    wprep_off_kernel<<<(32 * 9 * 128 + 255) / 256, blk, 0, stream>>>(
        P2[2], P2[3], P2[8], P2[9], wo2, bo2, 128);

    transpose_x_kernel<<<dim3(100, 4, B_), blk, 0, stream>>>(x, xp1, 256);

    BlkBuf B1 = {xp1, abuf, bqx, bqy, xp2, off4, stat1, scx, shx, scy, shy,
                 bo1, wc1, wdx1, wdy1, wf1, wo1};
    run_block(B1, 256, 128, P1, /*out_pad=*/1, stream);

    BlkBuf B2 = {xp2, abuf, bqx, bqy, h2, off4, stat2, scx, shx, scy, shy,
                 bo2, wc2, wdx2, wdy2, wf2, wo2};
    run_block(B2, 128, 256, P2, /*out_pad=*/0, stream);

    final_add_kernel<<<dim3(100, 4, B_), blk, 0, stream>>>(x, h2, (float*)d_out, 256);
}